// Round 1
// baseline (3750.219 us; speedup 1.0000x reference)
//
#include <hip/hip_runtime.h>
#include <cstddef>
#include <cstdint>

#define EPSF 1e-5f

constexpr int BB = 32, SS = 512, DD = 512, HH = 8, DH = 64;
constexpr int NTOK = BB * SS;              // 16384 rows
constexpr size_t ND = (size_t)NTOK * DD;   // 8,388,608

__device__ __forceinline__ float sigmf(float v) { return 1.f / (1.f + __expf(-v)); }

// ---------------- LayerNorm: one wave per row (D=512 -> 8 f32/lane) -------------
__global__ __launch_bounds__(256) void ln_f32(const float* __restrict__ x,
                                              const float* __restrict__ g,
                                              const float* __restrict__ b,
                                              float* __restrict__ y) {
  const int lane = threadIdx.x & 63;
  const int row = blockIdx.x * 4 + (threadIdx.x >> 6);
  const float* xr = x + (size_t)row * 512;
  const float4 v0 = *(const float4*)&xr[lane << 2];
  const float4 v1 = *(const float4*)&xr[256 + (lane << 2)];
  float s = v0.x + v0.y + v0.z + v0.w + v1.x + v1.y + v1.z + v1.w;
#pragma unroll
  for (int o = 32; o > 0; o >>= 1) s += __shfl_xor(s, o);
  const float mean = s * (1.f / 512.f);
  float q = 0.f;
  q += (v0.x - mean) * (v0.x - mean); q += (v0.y - mean) * (v0.y - mean);
  q += (v0.z - mean) * (v0.z - mean); q += (v0.w - mean) * (v0.w - mean);
  q += (v1.x - mean) * (v1.x - mean); q += (v1.y - mean) * (v1.y - mean);
  q += (v1.z - mean) * (v1.z - mean); q += (v1.w - mean) * (v1.w - mean);
#pragma unroll
  for (int o = 32; o > 0; o >>= 1) q += __shfl_xor(q, o);
  const float rs = rsqrtf(q * (1.f / 512.f) + EPSF);
  const float4 g0 = *(const float4*)&g[lane << 2];
  const float4 g1 = *(const float4*)&g[256 + (lane << 2)];
  const float4 b0 = *(const float4*)&b[lane << 2];
  const float4 b1 = *(const float4*)&b[256 + (lane << 2)];
  float* yr = y + (size_t)row * 512;
  float4 o0, o1;
  o0.x = (v0.x - mean) * rs * g0.x + b0.x; o0.y = (v0.y - mean) * rs * g0.y + b0.y;
  o0.z = (v0.z - mean) * rs * g0.z + b0.z; o0.w = (v0.w - mean) * rs * g0.w + b0.w;
  o1.x = (v1.x - mean) * rs * g1.x + b1.x; o1.y = (v1.y - mean) * rs * g1.y + b1.y;
  o1.z = (v1.z - mean) * rs * g1.z + b1.z; o1.w = (v1.w - mean) * rs * g1.w + b1.w;
  *(float4*)&yr[lane << 2] = o0;
  *(float4*)&yr[256 + (lane << 2)] = o1;
}

// ---------------- Generic SGEMM: C[M,N] = act(A[M,K]*W[K,N] + bias) (+res) ------
// ACT: 0 none, 1 silu.  RES: 0 none, 1 C=res+v, 2 C=res+0.5*v.
template <int ACT, int RES, int HASBIAS>
__global__ __launch_bounds__(256) void gemm_f32(const float* __restrict__ A,
                                                const float* __restrict__ W,
                                                const float* __restrict__ bias,
                                                const float* __restrict__ res,
                                                float* __restrict__ C,
                                                int M, int K, int N) {
  __shared__ float As[16][68];  // [k][m], padded
  __shared__ float Ws[16][72];  // [k][n], padded
  const int t = threadIdx.x;
  const int n0 = blockIdx.x << 6, m0 = blockIdx.y << 6;
  const int tx = t & 15, ty = t >> 4;
  const int arow = t >> 2, acol = (t & 3) << 2;
  const int wrow = t >> 4, wcol = (t & 15) << 2;
  const float* Ap = A + (size_t)(m0 + arow) * K + acol;
  const float* Wp = W + (size_t)wrow * N + n0 + wcol;
  float acc[4][4] = {};
  for (int k0 = 0; k0 < K; k0 += 16) {
    const float4 av = *(const float4*)Ap;
    const float4 wv = *(const float4*)Wp;
    As[acol + 0][arow] = av.x;
    As[acol + 1][arow] = av.y;
    As[acol + 2][arow] = av.z;
    As[acol + 3][arow] = av.w;
    *(float4*)&Ws[wrow][wcol] = wv;
    __syncthreads();
#pragma unroll
    for (int kk = 0; kk < 16; ++kk) {
      const float4 a4 = *(const float4*)&As[kk][ty << 2];
      const float4 w4 = *(const float4*)&Ws[kk][tx << 2];
      const float aa[4] = {a4.x, a4.y, a4.z, a4.w};
      const float ww[4] = {w4.x, w4.y, w4.z, w4.w};
#pragma unroll
      for (int i = 0; i < 4; ++i)
#pragma unroll
        for (int j = 0; j < 4; ++j) acc[i][j] = fmaf(aa[i], ww[j], acc[i][j]);
    }
    __syncthreads();
    Ap += 16;
    Wp += (size_t)16 * N;
  }
  float bb[4] = {0.f, 0.f, 0.f, 0.f};
  if (HASBIAS) {
    const float4 bv = *(const float4*)&bias[n0 + (tx << 2)];
    bb[0] = bv.x; bb[1] = bv.y; bb[2] = bv.z; bb[3] = bv.w;
  }
#pragma unroll
  for (int i = 0; i < 4; ++i) {
    const size_t row = (size_t)(m0 + (ty << 2) + i);
    float v[4];
#pragma unroll
    for (int j = 0; j < 4; ++j) {
      v[j] = acc[i][j] + bb[j];
      if (ACT == 1) v[j] = v[j] * sigmf(v[j]);
    }
    float4 o = make_float4(v[0], v[1], v[2], v[3]);
    if (RES == 1) {
      const float4 r = *(const float4*)&res[row * N + n0 + (tx << 2)];
      o.x += r.x; o.y += r.y; o.z += r.z; o.w += r.w;
    } else if (RES == 2) {
      const float4 r = *(const float4*)&res[row * N + n0 + (tx << 2)];
      o.x = r.x + 0.5f * o.x; o.y = r.y + 0.5f * o.y;
      o.z = r.z + 0.5f * o.z; o.w = r.w + 0.5f * o.w;
    }
    *(float4*)&C[row * N + n0 + (tx << 2)] = o;
  }
}

// ------------- Sinusoidal PE ----------------------------------------------------
__global__ void pe_kernel(float* __restrict__ pe) {
  const int pos = blockIdx.x, ii = threadIdx.x;  // ii = 0..255
  const float ang = (float)pos * powf(10000.f, -(float)(2 * ii) / 512.f);
  pe[((size_t)pos << 9) + 2 * ii] = sinf(ang);
  pe[((size_t)pos << 9) + 2 * ii + 1] = cosf(ang);
}

// ------------- scores GEMM: out[bl,h,q,c] = sum_d (q[b,q,h,d]+addb[h,d]) * B -----
// b_batched=1: B[c,d] = Bsrc[(b*512+c)*512 + h*64 + d]  (content, vs K)
// b_batched=0: B[c,d] = Bsrc[c*512 + h*64 + d]          (pos, vs p)
__global__ __launch_bounds__(256) void attn_qkp(const float* __restrict__ qbuf,
                                                const float* __restrict__ addb,
                                                const float* __restrict__ Bsrc,
                                                const int b_batched,
                                                float* __restrict__ outbuf,
                                                const int b_base) {
  __shared__ float As[64][68];  // [d][q]
  __shared__ float Bs[64][68];  // [d][c]
  const int t = threadIdx.x;
  const int c0 = blockIdx.x << 6, q0 = blockIdx.y << 6;
  const int zb = blockIdx.z;
  const int h = zb & (HH - 1);
  const int b = b_base + (zb >> 3);
  const int lr = t >> 4;
  const int lc = (t & 15) << 2;
  const float4 uv = *(const float4*)&addb[(h << 6) + lc];
#pragma unroll
  for (int p = 0; p < 4; ++p) {
    const int r = (p << 4) + lr;
    const float4 av = *(const float4*)&qbuf[((size_t)((b << 9) + q0 + r) << 9) + (h << 6) + lc];
    As[lc + 0][r] = av.x + uv.x;
    As[lc + 1][r] = av.y + uv.y;
    As[lc + 2][r] = av.z + uv.z;
    As[lc + 3][r] = av.w + uv.w;
    float4 bv;
    if (b_batched) bv = *(const float4*)&Bsrc[((size_t)((b << 9) + c0 + r) << 9) + (h << 6) + lc];
    else           bv = *(const float4*)&Bsrc[((size_t)(c0 + r) << 9) + (h << 6) + lc];
    Bs[lc + 0][r] = bv.x;
    Bs[lc + 1][r] = bv.y;
    Bs[lc + 2][r] = bv.z;
    Bs[lc + 3][r] = bv.w;
  }
  __syncthreads();
  const int tx = t & 15, ty = t >> 4;
  float acc[4][4] = {};
#pragma unroll 8
  for (int kk = 0; kk < 64; ++kk) {
    const float4 a4 = *(const float4*)&As[kk][ty << 2];
    const float4 b4 = *(const float4*)&Bs[kk][tx << 2];
    const float aa[4] = {a4.x, a4.y, a4.z, a4.w};
    const float cc[4] = {b4.x, b4.y, b4.z, b4.w};
#pragma unroll
    for (int i = 0; i < 4; ++i)
#pragma unroll
      for (int j = 0; j < 4; ++j) acc[i][j] = fmaf(aa[i], cc[j], acc[i][j]);
  }
  const size_t obase = (size_t)((b - b_base) * HH + h) << 18;
#pragma unroll
  for (int i = 0; i < 4; ++i) {
    *(float4*)&outbuf[obase + ((size_t)(q0 + (ty << 2) + i) << 9) + c0 + (tx << 2)] =
        make_float4(acc[i][0], acc[i][1], acc[i][2], acc[i][3]);
  }
}

// ------------- rel_shift + scale + softmax (in-place on attn) -------------------
// shift(ps)[q,c] = ps[q, c-q+511] (c<=q) | 0 (c==q+1) | ps[q+1, c-q-2] (c>q+1)
__global__ __launch_bounds__(256) void fuse_softmax(float* __restrict__ attn,
                                                    const float* __restrict__ ps,
                                                    const int b0) {
  const int wid = blockIdx.x * 4 + (threadIdx.x >> 6);
  const int lane = threadIdx.x & 63;
  const int q = wid & 511;
  const int bhl = wid >> 9;  // local (b-b0)*H + h
  float* row = attn + (((size_t)(b0 * HH + bhl) << 9) + q) * 512;
  const float* psrow = ps + (((size_t)bhl << 9) + q) * 512;
  const float scale = 0.044194173824159216f;  // 1/sqrt(512)
  float vals[8];
#pragma unroll
  for (int j = 0; j < 8; ++j) {
    const int c = (j << 6) + lane;
    float f;
    if (c <= q)          f = psrow[c - q + 511];
    else if (c == q + 1) f = 0.f;
    else                 f = psrow[512 + c - q - 2];
    vals[j] = (row[c] + f) * scale;
  }
  float m = vals[0];
#pragma unroll
  for (int j = 1; j < 8; ++j) m = fmaxf(m, vals[j]);
#pragma unroll
  for (int o = 32; o > 0; o >>= 1) m = fmaxf(m, __shfl_xor(m, o));
  float s = 0.f;
#pragma unroll
  for (int j = 0; j < 8; ++j) { vals[j] = __expf(vals[j] - m); s += vals[j]; }
#pragma unroll
  for (int o = 32; o > 0; o >>= 1) s += __shfl_xor(s, o);
  const float inv = 1.f / s;
#pragma unroll
  for (int j = 0; j < 8; ++j) row[(j << 6) + lane] = vals[j] * inv;
}

// ------------- ctx GEMM: ctx[b,q,h,d] = sum_k attn[b,h,q,k] v[b,k,h,d] ----------
__global__ __launch_bounds__(256) void attn_ctx(const float* __restrict__ attn,
                                                const float* __restrict__ vbuf,
                                                float* __restrict__ ctx) {
  __shared__ float As[64][68];  // [k][q]
  __shared__ float Bs[64][72];  // [k][d]
  const int t = threadIdx.x;
  const int q0 = blockIdx.x << 6;
  const int zb = blockIdx.y;  // b*H + h
  const int h = zb & 7, b = zb >> 3;
  const int lr = t >> 4, lc = (t & 15) << 2;
  const int tx = t & 15, ty = t >> 4;
  const size_t abase = (size_t)zb << 18;
  float acc[4][4] = {};
  for (int k0 = 0; k0 < 512; k0 += 64) {
#pragma unroll
    for (int p = 0; p < 4; ++p) {
      const int r = (p << 4) + lr;
      const float4 av = *(const float4*)&attn[abase + ((size_t)(q0 + r) << 9) + k0 + lc];
      As[lc + 0][r] = av.x;
      As[lc + 1][r] = av.y;
      As[lc + 2][r] = av.z;
      As[lc + 3][r] = av.w;
      const float4 vv = *(const float4*)&vbuf[((size_t)((b << 9) + k0 + r) << 9) + (h << 6) + lc];
      *(float4*)&Bs[r][lc] = vv;
    }
    __syncthreads();
#pragma unroll 8
    for (int kk = 0; kk < 64; ++kk) {
      const float4 a4 = *(const float4*)&As[kk][ty << 2];
      const float4 b4 = *(const float4*)&Bs[kk][tx << 2];
      const float aa[4] = {a4.x, a4.y, a4.z, a4.w};
      const float cc[4] = {b4.x, b4.y, b4.z, b4.w};
#pragma unroll
      for (int i = 0; i < 4; ++i)
#pragma unroll
        for (int j = 0; j < 4; ++j) acc[i][j] = fmaf(aa[i], cc[j], acc[i][j]);
    }
    __syncthreads();
  }
#pragma unroll
  for (int i = 0; i < 4; ++i) {
    *(float4*)&ctx[((size_t)((b << 9) + q0 + (ty << 2) + i) << 9) + (h << 6) + (tx << 2)] =
        make_float4(acc[i][0], acc[i][1], acc[i][2], acc[i][3]);
  }
}

// ------------- GLU: out[n,d] = mid[n,d] * sigmoid(mid[n,512+d]) -----------------
__global__ __launch_bounds__(256) void glu_kernel(const float* __restrict__ mid,
                                                  float* __restrict__ out) {
  const int idx = blockIdx.x * 256 + threadIdx.x;
  const int r = idx >> 9, c = idx & 511;
  const float a = mid[((size_t)r << 10) + c];
  const float g = mid[((size_t)r << 10) + 512 + c];
  out[idx] = a * sigmf(g);
}

// ------------- depthwise conv (K=31) + BN + swish -------------------------------
__global__ __launch_bounds__(256) void dwconv_bn_silu(const float* __restrict__ in,
                                                      const float* __restrict__ w,
                                                      const float* __restrict__ bng,
                                                      const float* __restrict__ bnb,
                                                      const float* __restrict__ bnm,
                                                      const float* __restrict__ bnv,
                                                      float* __restrict__ out) {
  const int idx = blockIdx.x * 256 + threadIdx.x;
  const int d = idx & 511;
  const int s = (idx >> 9) & 511;
  const size_t bbase = ((size_t)(idx >> 18)) << 18;
  const float* col = in + bbase + d;
  float acc = 0.f;
#pragma unroll
  for (int t = 0; t < 31; ++t) {
    const int ss = s + t - 15;
    if (ss >= 0 && ss < 512) acc = fmaf(col[(size_t)ss << 9], w[d * 31 + t], acc);
  }
  const float vv = (acc - bnm[d]) * rsqrtf(bnv[d] + EPSF) * bng[d] + bnb[d];
  out[idx] = vv * sigmf(vv);
}

extern "C" void kernel_launch(void* const* d_in, const int* in_sizes, int n_in,
                              void* d_out, int out_size, void* d_ws, size_t ws_size,
                              hipStream_t stream) {
  const float* x      = (const float*)d_in[0];
  const float* ff1_g  = (const float*)d_in[1];
  const float* ff1_b  = (const float*)d_in[2];
  const float* ff1_w1 = (const float*)d_in[3];
  const float* ff1_b1 = (const float*)d_in[4];
  const float* ff1_w2 = (const float*)d_in[5];
  const float* ff1_b2 = (const float*)d_in[6];
  const float* attn_g = (const float*)d_in[7];
  const float* attn_b = (const float*)d_in[8];
  const float* wq     = (const float*)d_in[9];
  const float* bq     = (const float*)d_in[10];
  const float* wk     = (const float*)d_in[11];
  const float* bk     = (const float*)d_in[12];
  const float* wv     = (const float*)d_in[13];
  const float* bv     = (const float*)d_in[14];
  const float* wpos   = (const float*)d_in[15];
  const float* u_bias = (const float*)d_in[16];
  const float* v_bias = (const float*)d_in[17];
  const float* wo     = (const float*)d_in[18];
  const float* bo     = (const float*)d_in[19];
  const float* conv_g = (const float*)d_in[20];
  const float* conv_b = (const float*)d_in[21];
  const float* pw1_w  = (const float*)d_in[22];
  const float* pw1_b  = (const float*)d_in[23];
  const float* dw_w   = (const float*)d_in[24];
  const float* bn_g   = (const float*)d_in[25];
  const float* bn_b   = (const float*)d_in[26];
  const float* bn_m   = (const float*)d_in[27];
  const float* bn_v   = (const float*)d_in[28];
  const float* pw2_w  = (const float*)d_in[29];
  const float* pw2_b  = (const float*)d_in[30];
  const float* ff2_g  = (const float*)d_in[31];
  const float* ff2_b  = (const float*)d_in[32];
  const float* ff2_w1 = (const float*)d_in[33];
  const float* ff2_b1 = (const float*)d_in[34];
  const float* ff2_w2 = (const float*)d_in[35];
  const float* ff2_b2 = (const float*)d_in[36];
  const float* ln_g   = (const float*)d_in[37];
  const float* ln_b   = (const float*)d_in[38];

  float* out  = (float*)d_out;            // [B,S,D]
  float* attn = out + ND;                 // [B,H,S,S]

  // workspace layout (floats): res(ND) | ybuf(ND) | big(4*ND) | pe(S*D) | p(S*D)
  float* res  = (float*)d_ws;
  float* ybuf = res + ND;
  float* big  = ybuf + ND;
  float* pe   = big + 4 * ND;
  float* pp   = pe + (size_t)SS * DD;
  float* qb = big;
  float* kb = big + ND;
  float* vb = big + 2 * ND;

  const dim3 blk(256);

  // ---- Macaron FF1: res = x + 0.5*FF(LN(x)) ----
  ln_f32<<<NTOK / 4, blk, 0, stream>>>(x, ff1_g, ff1_b, ybuf);
  gemm_f32<1, 0, 1><<<dim3(2048 / 64, NTOK / 64), blk, 0, stream>>>(
      ybuf, ff1_w1, ff1_b1, nullptr, big, NTOK, 512, 2048);
  gemm_f32<0, 2, 1><<<dim3(512 / 64, NTOK / 64), blk, 0, stream>>>(
      big, ff1_w2, ff1_b2, x, res, NTOK, 2048, 512);

  // ---- Attention ----
  ln_f32<<<NTOK / 4, blk, 0, stream>>>(res, attn_g, attn_b, ybuf);
  gemm_f32<0, 0, 1><<<dim3(8, NTOK / 64), blk, 0, stream>>>(ybuf, wq, bq, nullptr, qb, NTOK, 512, 512);
  gemm_f32<0, 0, 1><<<dim3(8, NTOK / 64), blk, 0, stream>>>(ybuf, wk, bk, nullptr, kb, NTOK, 512, 512);
  gemm_f32<0, 0, 1><<<dim3(8, NTOK / 64), blk, 0, stream>>>(ybuf, wv, bv, nullptr, vb, NTOK, 512, 512);
  pe_kernel<<<512, 256, 0, stream>>>(pe);
  gemm_f32<0, 0, 0><<<dim3(8, 8), blk, 0, stream>>>(pe, wpos, nullptr, nullptr, pp, 512, 512, 512);

  // content scores for all (b,h) into attn buffer
  attn_qkp<<<dim3(8, 8, BB * HH), blk, 0, stream>>>(qb, u_bias, kb, 1, attn, 0);
  // pos scores in groups of 4 batches (PS fits in ybuf), then shift+softmax
  for (int g = 0; g < 8; ++g) {
    attn_qkp<<<dim3(8, 8, 4 * HH), blk, 0, stream>>>(qb, v_bias, pp, 0, ybuf, g * 4);
    fuse_softmax<<<4 * HH * 512 / 4, blk, 0, stream>>>(attn, ybuf, g * 4);
  }
  // ctx into qb (q dead), then out-proj + residual
  attn_ctx<<<dim3(8, BB * HH), blk, 0, stream>>>(attn, vb, qb);
  gemm_f32<0, 1, 1><<<dim3(8, NTOK / 64), blk, 0, stream>>>(qb, wo, bo, res, res, NTOK, 512, 512);

  // ---- Conv module ----
  ln_f32<<<NTOK / 4, blk, 0, stream>>>(res, conv_g, conv_b, ybuf);
  gemm_f32<0, 0, 1><<<dim3(16, NTOK / 64), blk, 0, stream>>>(ybuf, pw1_w, pw1_b, nullptr, big, NTOK, 512, 1024);
  glu_kernel<<<(int)(ND / 256), blk, 0, stream>>>(big, ybuf);
  dwconv_bn_silu<<<(int)(ND / 256), blk, 0, stream>>>(ybuf, dw_w, bn_g, bn_b, bn_m, bn_v, big);
  gemm_f32<0, 1, 1><<<dim3(8, NTOK / 64), blk, 0, stream>>>(big, pw2_w, pw2_b, res, res, NTOK, 512, 512);

  // ---- Macaron FF2 + final LN ----
  ln_f32<<<NTOK / 4, blk, 0, stream>>>(res, ff2_g, ff2_b, ybuf);
  gemm_f32<1, 0, 1><<<dim3(2048 / 64, NTOK / 64), blk, 0, stream>>>(
      ybuf, ff2_w1, ff2_b1, nullptr, big, NTOK, 512, 2048);
  gemm_f32<0, 2, 1><<<dim3(512 / 64, NTOK / 64), blk, 0, stream>>>(
      big, ff2_w2, ff2_b2, res, res, NTOK, 2048, 512);
  ln_f32<<<NTOK / 4, blk, 0, stream>>>(res, ln_g, ln_b, out);
}

// Round 2
// 1461.136 us; speedup vs baseline: 2.5666x; 2.5666x over previous
//
#include <hip/hip_runtime.h>
#include <cstddef>
#include <cstdint>

#define EPSF 1e-5f

constexpr int BB = 32, SS = 512, DD = 512, HH = 8, DH = 64;
constexpr int NTOK = BB * SS;              // 16384 rows
constexpr size_t ND = (size_t)NTOK * DD;   // 8,388,608

typedef __attribute__((ext_vector_type(8))) short bf16x8;
typedef __attribute__((ext_vector_type(4))) float f32x4;

__device__ __forceinline__ float sigmf(float v) { return 1.f / (1.f + __expf(-v)); }

__device__ __forceinline__ ushort f2bf(float f) {
  union { float f; uint32_t u; } x{f};
  uint32_t r = x.u + 0x7FFF + ((x.u >> 16) & 1);
  return (ushort)(r >> 16);
}
__device__ __forceinline__ float bf2f(ushort u) {
  union { uint32_t u; float f; } x{(uint32_t)u << 16};
  return x.f;
}

// ---------------- LayerNorm: one wave per row, f32 out --------------------------
__global__ __launch_bounds__(256) void ln_f32(const float* __restrict__ x,
                                              const float* __restrict__ g,
                                              const float* __restrict__ b,
                                              float* __restrict__ y) {
  const int lane = threadIdx.x & 63;
  const int row = blockIdx.x * 4 + (threadIdx.x >> 6);
  const float* xr = x + (size_t)row * 512;
  const float4 v0 = *(const float4*)&xr[lane << 2];
  const float4 v1 = *(const float4*)&xr[256 + (lane << 2)];
  float s = v0.x + v0.y + v0.z + v0.w + v1.x + v1.y + v1.z + v1.w;
#pragma unroll
  for (int o = 32; o > 0; o >>= 1) s += __shfl_xor(s, o);
  const float mean = s * (1.f / 512.f);
  float q = 0.f;
  q += (v0.x - mean) * (v0.x - mean); q += (v0.y - mean) * (v0.y - mean);
  q += (v0.z - mean) * (v0.z - mean); q += (v0.w - mean) * (v0.w - mean);
  q += (v1.x - mean) * (v1.x - mean); q += (v1.y - mean) * (v1.y - mean);
  q += (v1.z - mean) * (v1.z - mean); q += (v1.w - mean) * (v1.w - mean);
#pragma unroll
  for (int o = 32; o > 0; o >>= 1) q += __shfl_xor(q, o);
  const float rs = rsqrtf(q * (1.f / 512.f) + EPSF);
  const float4 g0 = *(const float4*)&g[lane << 2];
  const float4 g1 = *(const float4*)&g[256 + (lane << 2)];
  const float4 b0 = *(const float4*)&b[lane << 2];
  const float4 b1 = *(const float4*)&b[256 + (lane << 2)];
  float* yr = y + (size_t)row * 512;
  float4 o0, o1;
  o0.x = (v0.x - mean) * rs * g0.x + b0.x; o0.y = (v0.y - mean) * rs * g0.y + b0.y;
  o0.z = (v0.z - mean) * rs * g0.z + b0.z; o0.w = (v0.w - mean) * rs * g0.w + b0.w;
  o1.x = (v1.x - mean) * rs * g1.x + b1.x; o1.y = (v1.y - mean) * rs * g1.y + b1.y;
  o1.z = (v1.z - mean) * rs * g1.z + b1.z; o1.w = (v1.w - mean) * rs * g1.w + b1.w;
  *(float4*)&yr[lane << 2] = o0;
  *(float4*)&yr[256 + (lane << 2)] = o1;
}

// ---------------- LayerNorm writing bf16 ----------------------------------------
__global__ __launch_bounds__(256) void ln_bf16(const float* __restrict__ x,
                                               const float* __restrict__ g,
                                               const float* __restrict__ b,
                                               ushort* __restrict__ y) {
  const int lane = threadIdx.x & 63;
  const int row = blockIdx.x * 4 + (threadIdx.x >> 6);
  const float* xr = x + (size_t)row * 512;
  const float4 v0 = *(const float4*)&xr[lane << 2];
  const float4 v1 = *(const float4*)&xr[256 + (lane << 2)];
  float s = v0.x + v0.y + v0.z + v0.w + v1.x + v1.y + v1.z + v1.w;
#pragma unroll
  for (int o = 32; o > 0; o >>= 1) s += __shfl_xor(s, o);
  const float mean = s * (1.f / 512.f);
  float q = 0.f;
  q += (v0.x - mean) * (v0.x - mean); q += (v0.y - mean) * (v0.y - mean);
  q += (v0.z - mean) * (v0.z - mean); q += (v0.w - mean) * (v0.w - mean);
  q += (v1.x - mean) * (v1.x - mean); q += (v1.y - mean) * (v1.y - mean);
  q += (v1.z - mean) * (v1.z - mean); q += (v1.w - mean) * (v1.w - mean);
#pragma unroll
  for (int o = 32; o > 0; o >>= 1) q += __shfl_xor(q, o);
  const float rs = rsqrtf(q * (1.f / 512.f) + EPSF);
  const float4 g0 = *(const float4*)&g[lane << 2];
  const float4 g1 = *(const float4*)&g[256 + (lane << 2)];
  const float4 b0 = *(const float4*)&b[lane << 2];
  const float4 b1 = *(const float4*)&b[256 + (lane << 2)];
  ushort* yr = y + (size_t)row * 512;
  ushort4 o0, o1;
  o0.x = f2bf((v0.x - mean) * rs * g0.x + b0.x); o0.y = f2bf((v0.y - mean) * rs * g0.y + b0.y);
  o0.z = f2bf((v0.z - mean) * rs * g0.z + b0.z); o0.w = f2bf((v0.w - mean) * rs * g0.w + b0.w);
  o1.x = f2bf((v1.x - mean) * rs * g1.x + b1.x); o1.y = f2bf((v1.y - mean) * rs * g1.y + b1.y);
  o1.z = f2bf((v1.z - mean) * rs * g1.z + b1.z); o1.w = f2bf((v1.w - mean) * rs * g1.w + b1.w);
  *(ushort4*)&yr[lane << 2] = o0;
  *(ushort4*)&yr[256 + (lane << 2)] = o1;
}

// ---------------- Weight transpose + bf16 convert: [K,N] f32 -> [N,K] bf16 ------
__global__ __launch_bounds__(256) void transpose_bf16(const float* __restrict__ in,
                                                      ushort* __restrict__ out,
                                                      int K, int N) {
  __shared__ float tile[32][33];
  const int tx = threadIdx.x & 31, ty = threadIdx.x >> 5;
  const int n0 = blockIdx.x << 5, k0 = blockIdx.y << 5;
#pragma unroll
  for (int i = 0; i < 32; i += 8)
    tile[ty + i][tx] = in[(size_t)(k0 + ty + i) * N + n0 + tx];
  __syncthreads();
#pragma unroll
  for (int i = 0; i < 32; i += 8)
    out[(size_t)(n0 + ty + i) * K + k0 + tx] = f2bf(tile[tx][ty + i]);
}

// ---------------- bf16 MFMA GEMM: C = epi(A[M,K] * Wt[N,K]^T + bias) ------------
// 128x128 tile, BK=32, 4 waves (2x2), each 64x64 = 4x4 frags of 16x16x32.
// ACT: 0 none, 1 silu. RES: 0 none, 1 C=res+v, 2 C=res+0.5v. OBF: bf16 out.
template <int ACT, int RES, int OBF>
__global__ __launch_bounds__(256) void gemm_bf16(const ushort* __restrict__ A,
                                                 const ushort* __restrict__ Wt,
                                                 const float* __restrict__ bias,
                                                 const float* __restrict__ res,
                                                 void* __restrict__ Cv,
                                                 int M, int K, int N) {
  __shared__ ushort Al[2][128][40];  // +8 pad: row stride 80B -> ~2-way banks
  __shared__ ushort Bl[2][128][40];
  const int t = threadIdx.x;
  const int lane = t & 63;
  const int wave = t >> 6;
  const int wr = (wave >> 1) << 6, wc = (wave & 1) << 6;
  const int m0 = blockIdx.y << 7, n0 = blockIdx.x << 7;
  const int sr = t >> 2, sc = (t & 3) << 3;
  const ushort* Ap0 = A + (size_t)(m0 + sr) * K + sc;
  const ushort* Ap1 = Ap0 + (size_t)64 * K;
  const ushort* Bp0 = Wt + (size_t)(n0 + sr) * K + sc;
  const ushort* Bp1 = Bp0 + (size_t)64 * K;
  const int lm = lane & 15, lk = (lane >> 4) << 3;

  f32x4 acc[4][4];
#pragma unroll
  for (int i = 0; i < 4; ++i)
#pragma unroll
    for (int j = 0; j < 4; ++j) acc[i][j] = (f32x4)(0.f);

  bf16x8 ra0 = *(const bf16x8*)Ap0, ra1 = *(const bf16x8*)Ap1;
  bf16x8 rb0 = *(const bf16x8*)Bp0, rb1 = *(const bf16x8*)Bp1;
  const int NT = K >> 5;
  int cur = 0;
  for (int tt = 0; tt < NT; ++tt) {
    *(bf16x8*)&Al[cur][sr][sc] = ra0;
    *(bf16x8*)&Al[cur][sr + 64][sc] = ra1;
    *(bf16x8*)&Bl[cur][sr][sc] = rb0;
    *(bf16x8*)&Bl[cur][sr + 64][sc] = rb1;
    if (tt + 1 < NT) {
      const int ko = (tt + 1) << 5;
      ra0 = *(const bf16x8*)(Ap0 + ko); ra1 = *(const bf16x8*)(Ap1 + ko);
      rb0 = *(const bf16x8*)(Bp0 + ko); rb1 = *(const bf16x8*)(Bp1 + ko);
    }
    __syncthreads();
    bf16x8 af[4], bfr[4];
#pragma unroll
    for (int i = 0; i < 4; ++i) af[i] = *(const bf16x8*)&Al[cur][wr + i * 16 + lm][lk];
#pragma unroll
    for (int j = 0; j < 4; ++j) bfr[j] = *(const bf16x8*)&Bl[cur][wc + j * 16 + lm][lk];
#pragma unroll
    for (int i = 0; i < 4; ++i)
#pragma unroll
      for (int j = 0; j < 4; ++j)
        acc[i][j] = __builtin_amdgcn_mfma_f32_16x16x32_bf16(af[i], bfr[j], acc[i][j], 0, 0, 0);
    cur ^= 1;
  }

  float bb[4];
#pragma unroll
  for (int j = 0; j < 4; ++j) bb[j] = bias[n0 + wc + j * 16 + lm];
  const int rbase = m0 + wr + ((lane >> 4) << 2);
#pragma unroll
  for (int i = 0; i < 4; ++i) {
#pragma unroll
    for (int r = 0; r < 4; ++r) {
      const size_t row = (size_t)(rbase + i * 16 + r);
#pragma unroll
      for (int j = 0; j < 4; ++j) {
        const int col = n0 + wc + j * 16 + lm;
        float v = acc[i][j][r] + bb[j];
        if (ACT == 1) v = v * sigmf(v);
        if (RES == 1) v += res[row * N + col];
        else if (RES == 2) v = res[row * N + col] + 0.5f * v;
        if (OBF) ((ushort*)Cv)[row * N + col] = f2bf(v);
        else ((float*)Cv)[row * N + col] = v;
      }
    }
  }
}

// ---------------- f32 SGEMM (kept for pe*wpos only) -----------------------------
template <int ACT, int RES, int HASBIAS>
__global__ __launch_bounds__(256) void gemm_f32(const float* __restrict__ A,
                                                const float* __restrict__ W,
                                                const float* __restrict__ bias,
                                                const float* __restrict__ res,
                                                float* __restrict__ C,
                                                int M, int K, int N) {
  __shared__ float As[16][68];
  __shared__ float Ws[16][72];
  const int t = threadIdx.x;
  const int n0 = blockIdx.x << 6, m0 = blockIdx.y << 6;
  const int tx = t & 15, ty = t >> 4;
  const int arow = t >> 2, acol = (t & 3) << 2;
  const int wrow = t >> 4, wcol = (t & 15) << 2;
  const float* Ap = A + (size_t)(m0 + arow) * K + acol;
  const float* Wp = W + (size_t)wrow * N + n0 + wcol;
  float acc[4][4] = {};
  for (int k0 = 0; k0 < K; k0 += 16) {
    const float4 av = *(const float4*)Ap;
    const float4 wv = *(const float4*)Wp;
    As[acol + 0][arow] = av.x;
    As[acol + 1][arow] = av.y;
    As[acol + 2][arow] = av.z;
    As[acol + 3][arow] = av.w;
    *(float4*)&Ws[wrow][wcol] = wv;
    __syncthreads();
#pragma unroll
    for (int kk = 0; kk < 16; ++kk) {
      const float4 a4 = *(const float4*)&As[kk][ty << 2];
      const float4 w4 = *(const float4*)&Ws[kk][tx << 2];
      const float aa[4] = {a4.x, a4.y, a4.z, a4.w};
      const float ww[4] = {w4.x, w4.y, w4.z, w4.w};
#pragma unroll
      for (int i = 0; i < 4; ++i)
#pragma unroll
        for (int j = 0; j < 4; ++j) acc[i][j] = fmaf(aa[i], ww[j], acc[i][j]);
    }
    __syncthreads();
    Ap += 16;
    Wp += (size_t)16 * N;
  }
#pragma unroll
  for (int i = 0; i < 4; ++i) {
    const size_t row = (size_t)(m0 + (ty << 2) + i);
    *(float4*)&C[row * N + n0 + (tx << 2)] =
        make_float4(acc[i][0], acc[i][1], acc[i][2], acc[i][3]);
  }
}

// ------------- Sinusoidal PE ----------------------------------------------------
__global__ void pe_kernel(float* __restrict__ pe) {
  const int pos = blockIdx.x, ii = threadIdx.x;
  const float ang = (float)pos * powf(10000.f, -(float)(2 * ii) / 512.f);
  pe[((size_t)pos << 9) + 2 * ii] = sinf(ang);
  pe[((size_t)pos << 9) + 2 * ii + 1] = cosf(ang);
}

// ------------- scores GEMM (f32): out[bl,h,q,c] = sum_d (q+addb) * B ------------
__global__ __launch_bounds__(256) void attn_qkp(const float* __restrict__ qbuf,
                                                const float* __restrict__ addb,
                                                const float* __restrict__ Bsrc,
                                                const int b_batched,
                                                float* __restrict__ outbuf,
                                                const int b_base) {
  __shared__ float As[64][68];
  __shared__ float Bs[64][68];
  const int t = threadIdx.x;
  const int c0 = blockIdx.x << 6, q0 = blockIdx.y << 6;
  const int zb = blockIdx.z;
  const int h = zb & (HH - 1);
  const int b = b_base + (zb >> 3);
  const int lr = t >> 4;
  const int lc = (t & 15) << 2;
  const float4 uv = *(const float4*)&addb[(h << 6) + lc];
#pragma unroll
  for (int p = 0; p < 4; ++p) {
    const int r = (p << 4) + lr;
    const float4 av = *(const float4*)&qbuf[((size_t)((b << 9) + q0 + r) << 9) + (h << 6) + lc];
    As[lc + 0][r] = av.x + uv.x;
    As[lc + 1][r] = av.y + uv.y;
    As[lc + 2][r] = av.z + uv.z;
    As[lc + 3][r] = av.w + uv.w;
    float4 bv;
    if (b_batched) bv = *(const float4*)&Bsrc[((size_t)((b << 9) + c0 + r) << 9) + (h << 6) + lc];
    else           bv = *(const float4*)&Bsrc[((size_t)(c0 + r) << 9) + (h << 6) + lc];
    Bs[lc + 0][r] = bv.x;
    Bs[lc + 1][r] = bv.y;
    Bs[lc + 2][r] = bv.z;
    Bs[lc + 3][r] = bv.w;
  }
  __syncthreads();
  const int tx = t & 15, ty = t >> 4;
  float acc[4][4] = {};
#pragma unroll 8
  for (int kk = 0; kk < 64; ++kk) {
    const float4 a4 = *(const float4*)&As[kk][ty << 2];
    const float4 b4 = *(const float4*)&Bs[kk][tx << 2];
    const float aa[4] = {a4.x, a4.y, a4.z, a4.w};
    const float cc[4] = {b4.x, b4.y, b4.z, b4.w};
#pragma unroll
    for (int i = 0; i < 4; ++i)
#pragma unroll
      for (int j = 0; j < 4; ++j) acc[i][j] = fmaf(aa[i], cc[j], acc[i][j]);
  }
  const size_t obase = (size_t)((b - b_base) * HH + h) << 18;
#pragma unroll
  for (int i = 0; i < 4; ++i) {
    *(float4*)&outbuf[obase + ((size_t)(q0 + (ty << 2) + i) << 9) + c0 + (tx << 2)] =
        make_float4(acc[i][0], acc[i][1], acc[i][2], acc[i][3]);
  }
}

// ------------- rel_shift + scale + softmax (in-place on attn) -------------------
__global__ __launch_bounds__(256) void fuse_softmax(float* __restrict__ attn,
                                                    const float* __restrict__ ps,
                                                    const int b0) {
  const int wid = blockIdx.x * 4 + (threadIdx.x >> 6);
  const int lane = threadIdx.x & 63;
  const int q = wid & 511;
  const int bhl = wid >> 9;
  float* row = attn + (((size_t)(b0 * HH + bhl) << 9) + q) * 512;
  const float* psrow = ps + (((size_t)bhl << 9) + q) * 512;
  const float scale = 0.044194173824159216f;  // 1/sqrt(512)
  float vals[8];
#pragma unroll
  for (int j = 0; j < 8; ++j) {
    const int c = (j << 6) + lane;
    float f;
    if (c <= q)          f = psrow[c - q + 511];
    else if (c == q + 1) f = 0.f;
    else                 f = psrow[512 + c - q - 2];
    vals[j] = (row[c] + f) * scale;
  }
  float m = vals[0];
#pragma unroll
  for (int j = 1; j < 8; ++j) m = fmaxf(m, vals[j]);
#pragma unroll
  for (int o = 32; o > 0; o >>= 1) m = fmaxf(m, __shfl_xor(m, o));
  float s = 0.f;
#pragma unroll
  for (int j = 0; j < 8; ++j) { vals[j] = __expf(vals[j] - m); s += vals[j]; }
#pragma unroll
  for (int o = 32; o > 0; o >>= 1) s += __shfl_xor(s, o);
  const float inv = 1.f / s;
#pragma unroll
  for (int j = 0; j < 8; ++j) row[(j << 6) + lane] = vals[j] * inv;
}

// ------------- ctx GEMM: ctx[b,q,h,d] (bf16) = sum_k attn * v -------------------
__global__ __launch_bounds__(256) void attn_ctx(const float* __restrict__ attn,
                                                const float* __restrict__ vbuf,
                                                ushort* __restrict__ ctx) {
  __shared__ float As[64][68];
  __shared__ float Bs[64][72];
  const int t = threadIdx.x;
  const int q0 = blockIdx.x << 6;
  const int zb = blockIdx.y;
  const int h = zb & 7, b = zb >> 3;
  const int lr = t >> 4, lc = (t & 15) << 2;
  const int tx = t & 15, ty = t >> 4;
  const size_t abase = (size_t)zb << 18;
  float acc[4][4] = {};
  for (int k0 = 0; k0 < 512; k0 += 64) {
#pragma unroll
    for (int p = 0; p < 4; ++p) {
      const int r = (p << 4) + lr;
      const float4 av = *(const float4*)&attn[abase + ((size_t)(q0 + r) << 9) + k0 + lc];
      As[lc + 0][r] = av.x;
      As[lc + 1][r] = av.y;
      As[lc + 2][r] = av.z;
      As[lc + 3][r] = av.w;
      const float4 vv = *(const float4*)&vbuf[((size_t)((b << 9) + k0 + r) << 9) + (h << 6) + lc];
      *(float4*)&Bs[r][lc] = vv;
    }
    __syncthreads();
#pragma unroll 8
    for (int kk = 0; kk < 64; ++kk) {
      const float4 a4 = *(const float4*)&As[kk][ty << 2];
      const float4 b4 = *(const float4*)&Bs[kk][tx << 2];
      const float aa[4] = {a4.x, a4.y, a4.z, a4.w};
      const float cc[4] = {b4.x, b4.y, b4.z, b4.w};
#pragma unroll
      for (int i = 0; i < 4; ++i)
#pragma unroll
        for (int j = 0; j < 4; ++j) acc[i][j] = fmaf(aa[i], cc[j], acc[i][j]);
    }
    __syncthreads();
  }
#pragma unroll
  for (int i = 0; i < 4; ++i) {
    ushort4 o4;
    o4.x = f2bf(acc[i][0]); o4.y = f2bf(acc[i][1]);
    o4.z = f2bf(acc[i][2]); o4.w = f2bf(acc[i][3]);
    *(ushort4*)&ctx[((size_t)((b << 9) + q0 + (ty << 2) + i) << 9) + (h << 6) + (tx << 2)] = o4;
  }
}

// ------------- GLU: f32 in [n,1024] -> bf16 out [n,512] -------------------------
__global__ __launch_bounds__(256) void glu_kernel(const float* __restrict__ mid,
                                                  ushort* __restrict__ out) {
  const int idx = blockIdx.x * 256 + threadIdx.x;
  const int r = idx >> 9, c = idx & 511;
  const float a = mid[((size_t)r << 10) + c];
  const float g = mid[((size_t)r << 10) + 512 + c];
  out[idx] = f2bf(a * sigmf(g));
}

// ------------- depthwise conv (K=31) + BN + swish, bf16 in/out ------------------
__global__ __launch_bounds__(256) void dwconv_bn_silu(const ushort* __restrict__ in,
                                                      const float* __restrict__ w,
                                                      const float* __restrict__ bng,
                                                      const float* __restrict__ bnb,
                                                      const float* __restrict__ bnm,
                                                      const float* __restrict__ bnv,
                                                      ushort* __restrict__ out) {
  const int idx = blockIdx.x * 256 + threadIdx.x;
  const int d = idx & 511;
  const int s = (idx >> 9) & 511;
  const size_t bbase = ((size_t)(idx >> 18)) << 18;
  const ushort* col = in + bbase + d;
  float acc = 0.f;
#pragma unroll
  for (int t = 0; t < 31; ++t) {
    const int ss = s + t - 15;
    if (ss >= 0 && ss < 512) acc = fmaf(bf2f(col[(size_t)ss << 9]), w[d * 31 + t], acc);
  }
  const float vv = (acc - bnm[d]) * rsqrtf(bnv[d] + EPSF) * bng[d] + bnb[d];
  out[idx] = f2bf(vv * sigmf(vv));
}

extern "C" void kernel_launch(void* const* d_in, const int* in_sizes, int n_in,
                              void* d_out, int out_size, void* d_ws, size_t ws_size,
                              hipStream_t stream) {
  const float* x      = (const float*)d_in[0];
  const float* ff1_g  = (const float*)d_in[1];
  const float* ff1_b  = (const float*)d_in[2];
  const float* ff1_w1 = (const float*)d_in[3];
  const float* ff1_b1 = (const float*)d_in[4];
  const float* ff1_w2 = (const float*)d_in[5];
  const float* ff1_b2 = (const float*)d_in[6];
  const float* attn_g = (const float*)d_in[7];
  const float* attn_b = (const float*)d_in[8];
  const float* wq     = (const float*)d_in[9];
  const float* bq     = (const float*)d_in[10];
  const float* wk     = (const float*)d_in[11];
  const float* bk     = (const float*)d_in[12];
  const float* wv     = (const float*)d_in[13];
  const float* bv     = (const float*)d_in[14];
  const float* wpos   = (const float*)d_in[15];
  const float* u_bias = (const float*)d_in[16];
  const float* v_bias = (const float*)d_in[17];
  const float* wo     = (const float*)d_in[18];
  const float* bo     = (const float*)d_in[19];
  const float* conv_g = (const float*)d_in[20];
  const float* conv_b = (const float*)d_in[21];
  const float* pw1_w  = (const float*)d_in[22];
  const float* pw1_b  = (const float*)d_in[23];
  const float* dw_w   = (const float*)d_in[24];
  const float* bn_g   = (const float*)d_in[25];
  const float* bn_b   = (const float*)d_in[26];
  const float* bn_m   = (const float*)d_in[27];
  const float* bn_v   = (const float*)d_in[28];
  const float* pw2_w  = (const float*)d_in[29];
  const float* pw2_b  = (const float*)d_in[30];
  const float* ff2_g  = (const float*)d_in[31];
  const float* ff2_b  = (const float*)d_in[32];
  const float* ff2_w1 = (const float*)d_in[33];
  const float* ff2_b1 = (const float*)d_in[34];
  const float* ff2_w2 = (const float*)d_in[35];
  const float* ff2_b2 = (const float*)d_in[36];
  const float* ln_g   = (const float*)d_in[37];
  const float* ln_b   = (const float*)d_in[38];

  float* out  = (float*)d_out;            // [B,S,D] f32
  float* attn = out + ND;                 // [B,H,S,S] f32

  // workspace (floats): res ND | ybf ND/2 | big 2ND | vb ND | ps ND | wts ~3M | pe,pp
  float*  res   = (float*)d_ws;
  ushort* ybf   = (ushort*)(res + ND);           // ND bf16
  float*  big   = (float*)(ybf + ND);            // 2*ND f32 region
  float*  vb    = big + 2 * ND;                  // ND f32 (v); later GLU bf16 out
  float*  ps    = vb + ND;                       // ND f32 (4-batch pos scores)
  ushort* wts   = (ushort*)(ps + ND);            // 6,029,312 bf16
  float*  pe    = (float*)(wts + 6029312);
  float*  pp    = pe + (size_t)SS * DD;

  // big region aliases
  ushort* ffmid = (ushort*)big;                  // [M,2048] bf16
  float*  qb    = big;                           // [M,512] f32
  float*  kb    = big + ND;                      // [M,512] f32
  ushort* ctxbf = (ushort*)(big + ND);           // [M,512] bf16 (after kb dead)
  ushort* glubf = (ushort*)vb;                   // [M,512] bf16 (after v dead)
  ushort* dwbf  = ybf;                           // [M,512] bf16 (after LN consumed)

  // transposed bf16 weights
  ushort* ff1w1t = wts;                 // [2048,512]
  ushort* ff1w2t = wts + 1048576;       // [512,2048]
  ushort* wqt    = wts + 2097152;       // [512,512]
  ushort* wkt    = wts + 2359296;
  ushort* wvt    = wts + 2621440;
  ushort* wot    = wts + 2883584;
  ushort* pw1t   = wts + 3145728;       // [1024,512]
  ushort* pw2t   = wts + 3670016;       // [512,512]
  ushort* ff2w1t = wts + 3932160;       // [2048,512]
  ushort* ff2w2t = wts + 4980736;       // [512,2048]

  const dim3 blk(256);

  // ---- weight prep ----
  transpose_bf16<<<dim3(2048 / 32, 512 / 32), blk, 0, stream>>>(ff1_w1, ff1w1t, 512, 2048);
  transpose_bf16<<<dim3(512 / 32, 2048 / 32), blk, 0, stream>>>(ff1_w2, ff1w2t, 2048, 512);
  transpose_bf16<<<dim3(16, 16), blk, 0, stream>>>(wq, wqt, 512, 512);
  transpose_bf16<<<dim3(16, 16), blk, 0, stream>>>(wk, wkt, 512, 512);
  transpose_bf16<<<dim3(16, 16), blk, 0, stream>>>(wv, wvt, 512, 512);
  transpose_bf16<<<dim3(16, 16), blk, 0, stream>>>(wo, wot, 512, 512);
  transpose_bf16<<<dim3(1024 / 32, 16), blk, 0, stream>>>(pw1_w, pw1t, 512, 1024);
  transpose_bf16<<<dim3(16, 16), blk, 0, stream>>>(pw2_w, pw2t, 512, 512);
  transpose_bf16<<<dim3(2048 / 32, 512 / 32), blk, 0, stream>>>(ff2_w1, ff2w1t, 512, 2048);
  transpose_bf16<<<dim3(512 / 32, 2048 / 32), blk, 0, stream>>>(ff2_w2, ff2w2t, 2048, 512);
  pe_kernel<<<512, 256, 0, stream>>>(pe);
  gemm_f32<0, 0, 0><<<dim3(8, 8), blk, 0, stream>>>(pe, wpos, nullptr, nullptr, pp, 512, 512, 512);

  // ---- Macaron FF1: res = x + 0.5*FF(LN(x)) ----
  ln_bf16<<<NTOK / 4, blk, 0, stream>>>(x, ff1_g, ff1_b, ybf);
  gemm_bf16<1, 0, 1><<<dim3(16, 128), blk, 0, stream>>>(ybf, ff1w1t, ff1_b1, nullptr, ffmid,
                                                        NTOK, 512, 2048);
  gemm_bf16<0, 2, 0><<<dim3(4, 128), blk, 0, stream>>>(ffmid, ff1w2t, ff1_b2, x, res,
                                                       NTOK, 2048, 512);

  // ---- Attention ----
  ln_bf16<<<NTOK / 4, blk, 0, stream>>>(res, attn_g, attn_b, ybf);
  gemm_bf16<0, 0, 0><<<dim3(4, 128), blk, 0, stream>>>(ybf, wqt, bq, nullptr, qb, NTOK, 512, 512);
  gemm_bf16<0, 0, 0><<<dim3(4, 128), blk, 0, stream>>>(ybf, wkt, bk, nullptr, kb, NTOK, 512, 512);
  gemm_bf16<0, 0, 0><<<dim3(4, 128), blk, 0, stream>>>(ybf, wvt, bv, nullptr, vb, NTOK, 512, 512);

  attn_qkp<<<dim3(8, 8, BB * HH), blk, 0, stream>>>(qb, u_bias, kb, 1, attn, 0);
  for (int g = 0; g < 8; ++g) {
    attn_qkp<<<dim3(8, 8, 4 * HH), blk, 0, stream>>>(qb, v_bias, pp, 0, ps, g * 4);
    fuse_softmax<<<4 * HH * 512 / 4, blk, 0, stream>>>(attn, ps, g * 4);
  }
  attn_ctx<<<dim3(8, BB * HH), blk, 0, stream>>>(attn, vb, ctxbf);
  gemm_bf16<0, 1, 0><<<dim3(4, 128), blk, 0, stream>>>(ctxbf, wot, bo, res, res, NTOK, 512, 512);

  // ---- Conv module ----
  ln_bf16<<<NTOK / 4, blk, 0, stream>>>(res, conv_g, conv_b, ybf);
  gemm_bf16<0, 0, 0><<<dim3(8, 128), blk, 0, stream>>>(ybf, pw1t, pw1_b, nullptr, big,
                                                       NTOK, 512, 1024);
  glu_kernel<<<(int)(ND / 256), blk, 0, stream>>>(big, glubf);
  dwconv_bn_silu<<<(int)(ND / 256), blk, 0, stream>>>(glubf, dw_w, bn_g, bn_b, bn_m, bn_v, dwbf);
  gemm_bf16<0, 1, 0><<<dim3(4, 128), blk, 0, stream>>>(dwbf, pw2t, pw2_b, res, res, NTOK, 512, 512);

  // ---- Macaron FF2 + final LN ----
  ln_bf16<<<NTOK / 4, blk, 0, stream>>>(res, ff2_g, ff2_b, ybf);
  gemm_bf16<1, 0, 1><<<dim3(16, 128), blk, 0, stream>>>(ybf, ff2w1t, ff2_b1, nullptr, ffmid,
                                                        NTOK, 512, 2048);
  gemm_bf16<0, 2, 0><<<dim3(4, 128), blk, 0, stream>>>(ffmid, ff2w2t, ff2_b2, res, res,
                                                       NTOK, 2048, 512);
  ln_f32<<<NTOK / 4, blk, 0, stream>>>(res, ln_g, ln_b, out);
}

// Round 3
// 1007.722 us; speedup vs baseline: 3.7215x; 1.4499x over previous
//
#include <hip/hip_runtime.h>
#include <cstddef>
#include <cstdint>

#define EPSF 1e-5f

constexpr int BB = 32, SS = 512, DD = 512, HH = 8, DH = 64;
constexpr int NTOK = BB * SS;              // 16384 rows
constexpr size_t ND = (size_t)NTOK * DD;   // 8,388,608

typedef __attribute__((ext_vector_type(8))) short bf16x8;
typedef __attribute__((ext_vector_type(4))) float f32x4;

__device__ __forceinline__ float sigmf(float v) { return 1.f / (1.f + __expf(-v)); }

__device__ __forceinline__ ushort f2bf(float f) {
  union { float f; uint32_t u; } x{f};
  uint32_t r = x.u + 0x7FFF + ((x.u >> 16) & 1);
  return (ushort)(r >> 16);
}
__device__ __forceinline__ float bf2f(ushort u) {
  union { uint32_t u; float f; } x{(uint32_t)u << 16};
  return x.f;
}

// ---------------- LayerNorm: one wave per row, f32 out --------------------------
__global__ __launch_bounds__(256) void ln_f32(const float* __restrict__ x,
                                              const float* __restrict__ g,
                                              const float* __restrict__ b,
                                              float* __restrict__ y) {
  const int lane = threadIdx.x & 63;
  const int row = blockIdx.x * 4 + (threadIdx.x >> 6);
  const float* xr = x + (size_t)row * 512;
  const float4 v0 = *(const float4*)&xr[lane << 2];
  const float4 v1 = *(const float4*)&xr[256 + (lane << 2)];
  float s = v0.x + v0.y + v0.z + v0.w + v1.x + v1.y + v1.z + v1.w;
#pragma unroll
  for (int o = 32; o > 0; o >>= 1) s += __shfl_xor(s, o);
  const float mean = s * (1.f / 512.f);
  float q = 0.f;
  q += (v0.x - mean) * (v0.x - mean); q += (v0.y - mean) * (v0.y - mean);
  q += (v0.z - mean) * (v0.z - mean); q += (v0.w - mean) * (v0.w - mean);
  q += (v1.x - mean) * (v1.x - mean); q += (v1.y - mean) * (v1.y - mean);
  q += (v1.z - mean) * (v1.z - mean); q += (v1.w - mean) * (v1.w - mean);
#pragma unroll
  for (int o = 32; o > 0; o >>= 1) q += __shfl_xor(q, o);
  const float rs = rsqrtf(q * (1.f / 512.f) + EPSF);
  const float4 g0 = *(const float4*)&g[lane << 2];
  const float4 g1 = *(const float4*)&g[256 + (lane << 2)];
  const float4 b0 = *(const float4*)&b[lane << 2];
  const float4 b1 = *(const float4*)&b[256 + (lane << 2)];
  float* yr = y + (size_t)row * 512;
  float4 o0, o1;
  o0.x = (v0.x - mean) * rs * g0.x + b0.x; o0.y = (v0.y - mean) * rs * g0.y + b0.y;
  o0.z = (v0.z - mean) * rs * g0.z + b0.z; o0.w = (v0.w - mean) * rs * g0.w + b0.w;
  o1.x = (v1.x - mean) * rs * g1.x + b1.x; o1.y = (v1.y - mean) * rs * g1.y + b1.y;
  o1.z = (v1.z - mean) * rs * g1.z + b1.z; o1.w = (v1.w - mean) * rs * g1.w + b1.w;
  *(float4*)&yr[lane << 2] = o0;
  *(float4*)&yr[256 + (lane << 2)] = o1;
}

// ---------------- LayerNorm writing bf16 ----------------------------------------
__global__ __launch_bounds__(256) void ln_bf16(const float* __restrict__ x,
                                               const float* __restrict__ g,
                                               const float* __restrict__ b,
                                               ushort* __restrict__ y) {
  const int lane = threadIdx.x & 63;
  const int row = blockIdx.x * 4 + (threadIdx.x >> 6);
  const float* xr = x + (size_t)row * 512;
  const float4 v0 = *(const float4*)&xr[lane << 2];
  const float4 v1 = *(const float4*)&xr[256 + (lane << 2)];
  float s = v0.x + v0.y + v0.z + v0.w + v1.x + v1.y + v1.z + v1.w;
#pragma unroll
  for (int o = 32; o > 0; o >>= 1) s += __shfl_xor(s, o);
  const float mean = s * (1.f / 512.f);
  float q = 0.f;
  q += (v0.x - mean) * (v0.x - mean); q += (v0.y - mean) * (v0.y - mean);
  q += (v0.z - mean) * (v0.z - mean); q += (v0.w - mean) * (v0.w - mean);
  q += (v1.x - mean) * (v1.x - mean); q += (v1.y - mean) * (v1.y - mean);
  q += (v1.z - mean) * (v1.z - mean); q += (v1.w - mean) * (v1.w - mean);
#pragma unroll
  for (int o = 32; o > 0; o >>= 1) q += __shfl_xor(q, o);
  const float rs = rsqrtf(q * (1.f / 512.f) + EPSF);
  const float4 g0 = *(const float4*)&g[lane << 2];
  const float4 g1 = *(const float4*)&g[256 + (lane << 2)];
  const float4 b0 = *(const float4*)&b[lane << 2];
  const float4 b1 = *(const float4*)&b[256 + (lane << 2)];
  ushort* yr = y + (size_t)row * 512;
  ushort4 o0, o1;
  o0.x = f2bf((v0.x - mean) * rs * g0.x + b0.x); o0.y = f2bf((v0.y - mean) * rs * g0.y + b0.y);
  o0.z = f2bf((v0.z - mean) * rs * g0.z + b0.z); o0.w = f2bf((v0.w - mean) * rs * g0.w + b0.w);
  o1.x = f2bf((v1.x - mean) * rs * g1.x + b1.x); o1.y = f2bf((v1.y - mean) * rs * g1.y + b1.y);
  o1.z = f2bf((v1.z - mean) * rs * g1.z + b1.z); o1.w = f2bf((v1.w - mean) * rs * g1.w + b1.w);
  *(ushort4*)&yr[lane << 2] = o0;
  *(ushort4*)&yr[256 + (lane << 2)] = o1;
}

// ---------------- Weight transpose + bf16 convert: [K,N] f32 -> [N,K] bf16 ------
__global__ __launch_bounds__(256) void transpose_bf16(const float* __restrict__ in,
                                                      ushort* __restrict__ out,
                                                      int K, int N) {
  __shared__ float tile[32][33];
  const int tx = threadIdx.x & 31, ty = threadIdx.x >> 5;
  const int n0 = blockIdx.x << 5, k0 = blockIdx.y << 5;
#pragma unroll
  for (int i = 0; i < 32; i += 8)
    tile[ty + i][tx] = in[(size_t)(k0 + ty + i) * N + n0 + tx];
  __syncthreads();
#pragma unroll
  for (int i = 0; i < 32; i += 8)
    out[(size_t)(n0 + ty + i) * K + k0 + tx] = f2bf(tile[tx][ty + i]);
}

// ---------------- bf16 MFMA GEMM: C = epi(A[M,K] * Wt[N,K]^T + bias) ------------
template <int ACT, int RES, int HB, int OBF>
__global__ __launch_bounds__(256) void gemm_bf16(const ushort* __restrict__ A,
                                                 const ushort* __restrict__ Wt,
                                                 const float* __restrict__ bias,
                                                 const float* __restrict__ res,
                                                 void* __restrict__ Cv,
                                                 int M, int K, int N) {
  __shared__ ushort Al[2][128][40];
  __shared__ ushort Bl[2][128][40];
  const int t = threadIdx.x;
  const int lane = t & 63;
  const int wave = t >> 6;
  const int wr = (wave >> 1) << 6, wc = (wave & 1) << 6;
  const int m0 = blockIdx.y << 7, n0 = blockIdx.x << 7;
  const int sr = t >> 2, sc = (t & 3) << 3;
  const ushort* Ap0 = A + (size_t)(m0 + sr) * K + sc;
  const ushort* Ap1 = Ap0 + (size_t)64 * K;
  const ushort* Bp0 = Wt + (size_t)(n0 + sr) * K + sc;
  const ushort* Bp1 = Bp0 + (size_t)64 * K;
  const int lm = lane & 15, lk = (lane >> 4) << 3;

  f32x4 acc[4][4];
#pragma unroll
  for (int i = 0; i < 4; ++i)
#pragma unroll
    for (int j = 0; j < 4; ++j) acc[i][j] = (f32x4)(0.f);

  bf16x8 ra0 = *(const bf16x8*)Ap0, ra1 = *(const bf16x8*)Ap1;
  bf16x8 rb0 = *(const bf16x8*)Bp0, rb1 = *(const bf16x8*)Bp1;
  const int NT = K >> 5;
  int cur = 0;
  for (int tt = 0; tt < NT; ++tt) {
    *(bf16x8*)&Al[cur][sr][sc] = ra0;
    *(bf16x8*)&Al[cur][sr + 64][sc] = ra1;
    *(bf16x8*)&Bl[cur][sr][sc] = rb0;
    *(bf16x8*)&Bl[cur][sr + 64][sc] = rb1;
    if (tt + 1 < NT) {
      const int ko = (tt + 1) << 5;
      ra0 = *(const bf16x8*)(Ap0 + ko); ra1 = *(const bf16x8*)(Ap1 + ko);
      rb0 = *(const bf16x8*)(Bp0 + ko); rb1 = *(const bf16x8*)(Bp1 + ko);
    }
    __syncthreads();
    bf16x8 af[4], bfr[4];
#pragma unroll
    for (int i = 0; i < 4; ++i) af[i] = *(const bf16x8*)&Al[cur][wr + i * 16 + lm][lk];
#pragma unroll
    for (int j = 0; j < 4; ++j) bfr[j] = *(const bf16x8*)&Bl[cur][wc + j * 16 + lm][lk];
#pragma unroll
    for (int i = 0; i < 4; ++i)
#pragma unroll
      for (int j = 0; j < 4; ++j)
        acc[i][j] = __builtin_amdgcn_mfma_f32_16x16x32_bf16(af[i], bfr[j], acc[i][j], 0, 0, 0);
    cur ^= 1;
  }

  float bb[4] = {0.f, 0.f, 0.f, 0.f};
  if (HB) {
#pragma unroll
    for (int j = 0; j < 4; ++j) bb[j] = bias[n0 + wc + j * 16 + lm];
  }
  const int rbase = m0 + wr + ((lane >> 4) << 2);
#pragma unroll
  for (int i = 0; i < 4; ++i) {
#pragma unroll
    for (int r = 0; r < 4; ++r) {
      const size_t row = (size_t)(rbase + i * 16 + r);
#pragma unroll
      for (int j = 0; j < 4; ++j) {
        const int col = n0 + wc + j * 16 + lm;
        float v = acc[i][j][r] + bb[j];
        if (ACT == 1) v = v * sigmf(v);
        if (RES == 1) v += res[row * N + col];
        else if (RES == 2) v = res[row * N + col] + 0.5f * v;
        if (OBF) ((ushort*)Cv)[row * N + col] = f2bf(v);
        else ((float*)Cv)[row * N + col] = v;
      }
    }
  }
}

// ---------------- dual-output Q projection: qu = q+bq+u, qv = q+bq+v ------------
__global__ __launch_bounds__(256) void gemm_dual(const ushort* __restrict__ A,
                                                 const ushort* __restrict__ Wt,
                                                 const float* __restrict__ bias,
                                                 const float* __restrict__ ub,
                                                 const float* __restrict__ vb,
                                                 ushort* __restrict__ qu,
                                                 ushort* __restrict__ qv,
                                                 int M, int K, int N) {
  __shared__ ushort Al[2][128][40];
  __shared__ ushort Bl[2][128][40];
  const int t = threadIdx.x;
  const int lane = t & 63;
  const int wave = t >> 6;
  const int wr = (wave >> 1) << 6, wc = (wave & 1) << 6;
  const int m0 = blockIdx.y << 7, n0 = blockIdx.x << 7;
  const int sr = t >> 2, sc = (t & 3) << 3;
  const ushort* Ap0 = A + (size_t)(m0 + sr) * K + sc;
  const ushort* Ap1 = Ap0 + (size_t)64 * K;
  const ushort* Bp0 = Wt + (size_t)(n0 + sr) * K + sc;
  const ushort* Bp1 = Bp0 + (size_t)64 * K;
  const int lm = lane & 15, lk = (lane >> 4) << 3;
  f32x4 acc[4][4];
#pragma unroll
  for (int i = 0; i < 4; ++i)
#pragma unroll
    for (int j = 0; j < 4; ++j) acc[i][j] = (f32x4)(0.f);
  bf16x8 ra0 = *(const bf16x8*)Ap0, ra1 = *(const bf16x8*)Ap1;
  bf16x8 rb0 = *(const bf16x8*)Bp0, rb1 = *(const bf16x8*)Bp1;
  const int NT = K >> 5;
  int cur = 0;
  for (int tt = 0; tt < NT; ++tt) {
    *(bf16x8*)&Al[cur][sr][sc] = ra0;
    *(bf16x8*)&Al[cur][sr + 64][sc] = ra1;
    *(bf16x8*)&Bl[cur][sr][sc] = rb0;
    *(bf16x8*)&Bl[cur][sr + 64][sc] = rb1;
    if (tt + 1 < NT) {
      const int ko = (tt + 1) << 5;
      ra0 = *(const bf16x8*)(Ap0 + ko); ra1 = *(const bf16x8*)(Ap1 + ko);
      rb0 = *(const bf16x8*)(Bp0 + ko); rb1 = *(const bf16x8*)(Bp1 + ko);
    }
    __syncthreads();
    bf16x8 af[4], bfr[4];
#pragma unroll
    for (int i = 0; i < 4; ++i) af[i] = *(const bf16x8*)&Al[cur][wr + i * 16 + lm][lk];
#pragma unroll
    for (int j = 0; j < 4; ++j) bfr[j] = *(const bf16x8*)&Bl[cur][wc + j * 16 + lm][lk];
#pragma unroll
    for (int i = 0; i < 4; ++i)
#pragma unroll
      for (int j = 0; j < 4; ++j)
        acc[i][j] = __builtin_amdgcn_mfma_f32_16x16x32_bf16(af[i], bfr[j], acc[i][j], 0, 0, 0);
    cur ^= 1;
  }
  const int rbase = m0 + wr + ((lane >> 4) << 2);
#pragma unroll
  for (int i = 0; i < 4; ++i) {
#pragma unroll
    for (int r = 0; r < 4; ++r) {
      const size_t row = (size_t)(rbase + i * 16 + r);
#pragma unroll
      for (int j = 0; j < 4; ++j) {
        const int col = n0 + wc + j * 16 + lm;
        const float v = acc[i][j][r] + bias[col];
        qu[row * N + col] = f2bf(v + ub[col]);
        qv[row * N + col] = f2bf(v + vb[col]);
      }
    }
  }
}

// ------------- Sinusoidal PE (bf16) ---------------------------------------------
__global__ void pe_kernel_bf16(ushort* __restrict__ pe) {
  const int pos = blockIdx.x, ii = threadIdx.x;
  const float ang = (float)pos * powf(10000.f, -(float)(2 * ii) / 512.f);
  pe[((size_t)pos << 9) + 2 * ii] = f2bf(sinf(ang));
  pe[((size_t)pos << 9) + 2 * ii + 1] = f2bf(cosf(ang));
}

// ------------- PS = (q+v) . pp^T per (b,h): psg[z][q][j] bf16 -------------------
__global__ __launch_bounds__(256) void ps_gemm(const ushort* __restrict__ qv,
                                               const ushort* __restrict__ ppb,
                                               ushort* __restrict__ psg,
                                               const int b0) {
  __shared__ ushort Plds[2][128][72];
  const int t = threadIdx.x, lane = t & 63, w = t >> 6;
  const int z = blockIdx.y;
  const int b = b0 + (z >> 3), h = z & 7;
  const int q0 = blockIdx.x << 6;
  const int lm = lane & 15, lk = (lane >> 4) << 3;
  const size_t abase = ((size_t)((b << 9) + q0 + (w << 4) + lm)) * 512 + (h << 6) + lk;
  const bf16x8 af0 = *(const bf16x8*)&qv[abase];
  const bf16x8 af1 = *(const bf16x8*)&qv[abase + 32];
  const int srow = t >> 3, scol = (t & 7) << 3;
  const ushort* pbase = ppb + (h << 6);
  f32x4 acc[32];
#pragma unroll
  for (int i = 0; i < 32; ++i) acc[i] = (f32x4)(0.f);
  bf16x8 kreg[4];
#pragma unroll
  for (int it = 0; it < 4; ++it)
    kreg[it] = *(const bf16x8*)&pbase[(size_t)((it << 5) + srow) * 512 + scol];
#pragma unroll
  for (int it = 0; it < 4; ++it) *(bf16x8*)&Plds[0][(it << 5) + srow][scol] = kreg[it];
  int cur = 0;
#pragma unroll
  for (int tile = 0; tile < 4; ++tile) {
    if (tile < 3) {
#pragma unroll
      for (int it = 0; it < 4; ++it)
        kreg[it] = *(const bf16x8*)&pbase[(size_t)((tile + 1) * 128 + (it << 5) + srow) * 512 + scol];
    }
    __syncthreads();
    if (tile < 3) {
#pragma unroll
      for (int it = 0; it < 4; ++it) *(bf16x8*)&Plds[cur ^ 1][(it << 5) + srow][scol] = kreg[it];
    }
#pragma unroll
    for (int sct = 0; sct < 8; ++sct) {
      const int ct = (tile << 3) + sct;
      const bf16x8 bf0 = *(const bf16x8*)&Plds[cur][(sct << 4) + lm][lk];
      const bf16x8 bf1 = *(const bf16x8*)&Plds[cur][(sct << 4) + lm][lk + 32];
      acc[ct] = __builtin_amdgcn_mfma_f32_16x16x32_bf16(af0, bf0, acc[ct], 0, 0, 0);
      acc[ct] = __builtin_amdgcn_mfma_f32_16x16x32_bf16(af1, bf1, acc[ct], 0, 0, 0);
    }
    cur ^= 1;
  }
  ushort* prow = psg + ((size_t)z << 18);
  const int qb_ = q0 + (w << 4) + ((lane >> 4) << 2);
#pragma unroll
  for (int ct = 0; ct < 32; ++ct)
#pragma unroll
    for (int r = 0; r < 4; ++r)
      prow[(size_t)(qb_ + r) * 512 + (ct << 4) + lm] = f2bf(acc[ct][r]);
}

// ------------- fused content-MFMA + rel-shift gather + softmax ------------------
__global__ __launch_bounds__(256) void attn_fused(const ushort* __restrict__ qu,
                                                  const ushort* __restrict__ kbb,
                                                  const ushort* __restrict__ psg,
                                                  float* __restrict__ attn,
                                                  const int b0) {
  __shared__ ushort Klds[2][128][72];
  const int t = threadIdx.x, lane = t & 63, w = t >> 6;
  const int z = blockIdx.y;
  const int b = b0 + (z >> 3), h = z & 7;
  const int q0 = blockIdx.x << 6;
  const int lm = lane & 15, lk = (lane >> 4) << 3;
  const size_t abase = ((size_t)((b << 9) + q0 + (w << 4) + lm)) * 512 + (h << 6) + lk;
  const bf16x8 af0 = *(const bf16x8*)&qu[abase];
  const bf16x8 af1 = *(const bf16x8*)&qu[abase + 32];
  const int srow = t >> 3, scol = (t & 7) << 3;
  const ushort* kbase = kbb + ((size_t)(b << 9)) * 512 + (h << 6);
  f32x4 acc[32];
#pragma unroll
  for (int i = 0; i < 32; ++i) acc[i] = (f32x4)(0.f);
  bf16x8 kreg[4];
#pragma unroll
  for (int it = 0; it < 4; ++it)
    kreg[it] = *(const bf16x8*)&kbase[(size_t)((it << 5) + srow) * 512 + scol];
#pragma unroll
  for (int it = 0; it < 4; ++it) *(bf16x8*)&Klds[0][(it << 5) + srow][scol] = kreg[it];
  int cur = 0;
#pragma unroll
  for (int tile = 0; tile < 4; ++tile) {
    if (tile < 3) {
#pragma unroll
      for (int it = 0; it < 4; ++it)
        kreg[it] = *(const bf16x8*)&kbase[(size_t)((tile + 1) * 128 + (it << 5) + srow) * 512 + scol];
    }
    __syncthreads();
    if (tile < 3) {
#pragma unroll
      for (int it = 0; it < 4; ++it) *(bf16x8*)&Klds[cur ^ 1][(it << 5) + srow][scol] = kreg[it];
    }
#pragma unroll
    for (int sct = 0; sct < 8; ++sct) {
      const int ct = (tile << 3) + sct;
      const bf16x8 bf0 = *(const bf16x8*)&Klds[cur][(sct << 4) + lm][lk];
      const bf16x8 bf1 = *(const bf16x8*)&Klds[cur][(sct << 4) + lm][lk + 32];
      acc[ct] = __builtin_amdgcn_mfma_f32_16x16x32_bf16(af0, bf0, acc[ct], 0, 0, 0);
      acc[ct] = __builtin_amdgcn_mfma_f32_16x16x32_bf16(af1, bf1, acc[ct], 0, 0, 0);
    }
    cur ^= 1;
  }
  // rel-shift gather from psg + scale
  const float scale = 0.044194173824159216f;  // 1/sqrt(512)
  const ushort* prow = psg + ((size_t)z << 18);
  const int qb_ = q0 + (w << 4) + ((lane >> 4) << 2);
#pragma unroll
  for (int ct = 0; ct < 32; ++ct) {
#pragma unroll
    for (int r = 0; r < 4; ++r) {
      const int q = qb_ + r;
      const int c = (ct << 4) + lm;
      float f;
      if (c <= q)          f = bf2f(prow[(size_t)q * 512 + c - q + 511]);
      else if (c == q + 1) f = 0.f;
      else                 f = bf2f(prow[(size_t)(q + 1) * 512 + c - q - 2]);
      acc[ct][r] = (acc[ct][r] + f) * scale;
    }
  }
  // softmax over c (512) per row
  float mx[4] = {-3.0e38f, -3.0e38f, -3.0e38f, -3.0e38f};
#pragma unroll
  for (int ct = 0; ct < 32; ++ct)
#pragma unroll
    for (int r = 0; r < 4; ++r) mx[r] = fmaxf(mx[r], acc[ct][r]);
#pragma unroll
  for (int o = 1; o < 16; o <<= 1)
#pragma unroll
    for (int r = 0; r < 4; ++r) mx[r] = fmaxf(mx[r], __shfl_xor(mx[r], o));
  float sm[4] = {0.f, 0.f, 0.f, 0.f};
#pragma unroll
  for (int ct = 0; ct < 32; ++ct)
#pragma unroll
    for (int r = 0; r < 4; ++r) {
      acc[ct][r] = __expf(acc[ct][r] - mx[r]);
      sm[r] += acc[ct][r];
    }
#pragma unroll
  for (int o = 1; o < 16; o <<= 1)
#pragma unroll
    for (int r = 0; r < 4; ++r) sm[r] += __shfl_xor(sm[r], o);
  float inv[4];
#pragma unroll
  for (int r = 0; r < 4; ++r) inv[r] = 1.f / sm[r];
  float* arow = attn + ((size_t)((b << 3) + h) << 18);
#pragma unroll
  for (int ct = 0; ct < 32; ++ct)
#pragma unroll
    for (int r = 0; r < 4; ++r)
      arow[(size_t)(qb_ + r) * 512 + (ct << 4) + lm] = acc[ct][r] * inv[r];
}

// ------------- V transpose: vbb [b,s,h*64+dh] -> vT [bh][dh][s] -----------------
__global__ __launch_bounds__(256) void transpose_v(const ushort* __restrict__ vbb,
                                                   ushort* __restrict__ vT) {
  __shared__ ushort tl[64][72];
  const int t = threadIdx.x;
  const int s0 = blockIdx.x << 6;
  const int z = blockIdx.y;
  const int b = z >> 3, h = z & 7;
  const int srow = t >> 3, scol = (t & 7) << 3;
#pragma unroll
  for (int it = 0; it < 2; ++it) {
    const int r = (it << 5) + srow;
    *(bf16x8*)&tl[r][scol] =
        *(const bf16x8*)&vbb[((size_t)((b << 9) + s0 + r)) * 512 + (h << 6) + scol];
  }
  __syncthreads();
#pragma unroll
  for (int it = 0; it < 2; ++it) {
    const int dh = (it << 5) + srow;
    ushort tmp[8];
#pragma unroll
    for (int k = 0; k < 8; ++k) tmp[k] = tl[scol + k][dh];
    *(bf16x8*)&vT[((size_t)((z << 6) + dh)) * 512 + s0 + scol] = *(bf16x8*)tmp;
  }
}

// ------------- ctx = attn . V via MFMA: ctx[b,q,h*64+d] bf16 --------------------
__global__ __launch_bounds__(256) void attn_ctx_mfma(const float* __restrict__ attn,
                                                     const ushort* __restrict__ vT,
                                                     ushort* __restrict__ ctx) {
  __shared__ ushort Alds[64][72];
  __shared__ ushort Vlds[64][72];
  const int t = threadIdx.x, lane = t & 63, w = t >> 6;
  const int q0 = blockIdx.x << 6;
  const int z = blockIdx.y;
  const int b = z >> 3, h = z & 7;
  const int lm = lane & 15, lk = (lane >> 4) << 3;
  const size_t abase = (size_t)z << 18;
  f32x4 acc[4];
#pragma unroll
  for (int i = 0; i < 4; ++i) acc[i] = (f32x4)(0.f);
  for (int k0 = 0; k0 < 512; k0 += 64) {
    __syncthreads();
    {
      const int ar = t >> 2, ac = (t & 3) << 4;
      const float* src = &attn[abase + (size_t)(q0 + ar) * 512 + k0 + ac];
      ushort tmp[16];
#pragma unroll
      for (int k = 0; k < 16; k += 4) {
        const float4 v4 = *(const float4*)&src[k];
        tmp[k] = f2bf(v4.x); tmp[k + 1] = f2bf(v4.y);
        tmp[k + 2] = f2bf(v4.z); tmp[k + 3] = f2bf(v4.w);
      }
      *(bf16x8*)&Alds[ar][ac] = *(bf16x8*)&tmp[0];
      *(bf16x8*)&Alds[ar][ac + 8] = *(bf16x8*)&tmp[8];
    }
    {
      const int vr = t >> 3, vc = (t & 7) << 3;
#pragma unroll
      for (int it = 0; it < 2; ++it)
        *(bf16x8*)&Vlds[(it << 5) + vr][vc] =
            *(const bf16x8*)&vT[((size_t)((z << 6) + (it << 5) + vr)) * 512 + k0 + vc];
    }
    __syncthreads();
    const bf16x8 af0 = *(const bf16x8*)&Alds[(w << 4) + lm][lk];
    const bf16x8 af1 = *(const bf16x8*)&Alds[(w << 4) + lm][lk + 32];
#pragma unroll
    for (int dt = 0; dt < 4; ++dt) {
      const bf16x8 bf0 = *(const bf16x8*)&Vlds[(dt << 4) + lm][lk];
      const bf16x8 bf1 = *(const bf16x8*)&Vlds[(dt << 4) + lm][lk + 32];
      acc[dt] = __builtin_amdgcn_mfma_f32_16x16x32_bf16(af0, bf0, acc[dt], 0, 0, 0);
      acc[dt] = __builtin_amdgcn_mfma_f32_16x16x32_bf16(af1, bf1, acc[dt], 0, 0, 0);
    }
  }
  const int qb_ = q0 + (w << 4) + ((lane >> 4) << 2);
#pragma unroll
  for (int dt = 0; dt < 4; ++dt)
#pragma unroll
    for (int r = 0; r < 4; ++r)
      ctx[((size_t)((b << 9) + qb_ + r)) * 512 + (h << 6) + (dt << 4) + lm] = f2bf(acc[dt][r]);
}

// ------------- GLU vectorized: f32 [M,1024] -> bf16 [M,512] ---------------------
__global__ __launch_bounds__(256) void glu8(const float* __restrict__ mid,
                                            ushort* __restrict__ out) {
  const int tid = blockIdx.x * 256 + threadIdx.x;
  const int r = tid >> 6;
  const int c = (tid & 63) << 3;
  const float* mrow = mid + ((size_t)r << 10);
  const float4 a0 = *(const float4*)&mrow[c];
  const float4 a1 = *(const float4*)&mrow[c + 4];
  const float4 g0 = *(const float4*)&mrow[512 + c];
  const float4 g1 = *(const float4*)&mrow[512 + c + 4];
  ushort tmp[8];
  tmp[0] = f2bf(a0.x * sigmf(g0.x)); tmp[1] = f2bf(a0.y * sigmf(g0.y));
  tmp[2] = f2bf(a0.z * sigmf(g0.z)); tmp[3] = f2bf(a0.w * sigmf(g0.w));
  tmp[4] = f2bf(a1.x * sigmf(g1.x)); tmp[5] = f2bf(a1.y * sigmf(g1.y));
  tmp[6] = f2bf(a1.z * sigmf(g1.z)); tmp[7] = f2bf(a1.w * sigmf(g1.w));
  *(bf16x8*)&out[((size_t)r << 9) + c] = *(bf16x8*)tmp;
}

// ------------- depthwise conv (K=31) + BN + swish, register sliding window ------
__global__ __launch_bounds__(256) void dwconv2(const ushort* __restrict__ in,
                                               const float* __restrict__ w,
                                               const float* __restrict__ bng,
                                               const float* __restrict__ bnb,
                                               const float* __restrict__ bnm,
                                               const float* __restrict__ bnv,
                                               ushort* __restrict__ out) {
  __shared__ float wl[31][128];
  const int t = threadIdx.x;
  const int dbase = blockIdx.x << 7;
  const int b = blockIdx.z;
  const int sb = (blockIdx.y << 6) + ((t >> 6) << 4);
  if (t < 128) {
    const float* ws = &w[(dbase + t) * 31];
#pragma unroll
    for (int k = 0; k < 31; ++k) wl[k][t] = ws[k];
  }
  __syncthreads();
  const int dl = (t & 63) << 1;
  const int d = dbase + dl;
  const size_t base = (((size_t)b) << 18) + d;
  float2 win[46];
#pragma unroll
  for (int i = 0; i < 46; ++i) {
    const int s = sb - 15 + i;
    if (s >= 0 && s < 512) {
      const ushort2 u = *(const ushort2*)&in[base + ((size_t)s << 9)];
      win[i].x = bf2f(u.x); win[i].y = bf2f(u.y);
    } else {
      win[i].x = 0.f; win[i].y = 0.f;
    }
  }
  float2 acc[16];
#pragma unroll
  for (int p = 0; p < 16; ++p) { acc[p].x = 0.f; acc[p].y = 0.f; }
#pragma unroll
  for (int k = 0; k < 31; ++k) {
    const float2 w2 = *(const float2*)&wl[k][dl];
#pragma unroll
    for (int p = 0; p < 16; ++p) {
      acc[p].x = fmaf(win[p + k].x, w2.x, acc[p].x);
      acc[p].y = fmaf(win[p + k].y, w2.y, acc[p].y);
    }
  }
  const float g0 = bng[d] * rsqrtf(bnv[d] + EPSF);
  const float g1 = bng[d + 1] * rsqrtf(bnv[d + 1] + EPSF);
  const float m0 = bnm[d], m1 = bnm[d + 1];
  const float bb0 = bnb[d], bb1 = bnb[d + 1];
#pragma unroll
  for (int p = 0; p < 16; ++p) {
    float v0 = (acc[p].x - m0) * g0 + bb0;
    float v1 = (acc[p].y - m1) * g1 + bb1;
    v0 = v0 * sigmf(v0);
    v1 = v1 * sigmf(v1);
    ushort2 o;
    o.x = f2bf(v0); o.y = f2bf(v1);
    *(ushort2*)&out[base + ((size_t)(sb + p) << 9)] = o;
  }
}

extern "C" void kernel_launch(void* const* d_in, const int* in_sizes, int n_in,
                              void* d_out, int out_size, void* d_ws, size_t ws_size,
                              hipStream_t stream) {
  const float* x      = (const float*)d_in[0];
  const float* ff1_g  = (const float*)d_in[1];
  const float* ff1_b  = (const float*)d_in[2];
  const float* ff1_w1 = (const float*)d_in[3];
  const float* ff1_b1 = (const float*)d_in[4];
  const float* ff1_w2 = (const float*)d_in[5];
  const float* ff1_b2 = (const float*)d_in[6];
  const float* attn_g = (const float*)d_in[7];
  const float* attn_b = (const float*)d_in[8];
  const float* wq     = (const float*)d_in[9];
  const float* bq     = (const float*)d_in[10];
  const float* wk     = (const float*)d_in[11];
  const float* bk     = (const float*)d_in[12];
  const float* wv     = (const float*)d_in[13];
  const float* bv     = (const float*)d_in[14];
  const float* wpos   = (const float*)d_in[15];
  const float* u_bias = (const float*)d_in[16];
  const float* v_bias = (const float*)d_in[17];
  const float* wo     = (const float*)d_in[18];
  const float* bo     = (const float*)d_in[19];
  const float* conv_g = (const float*)d_in[20];
  const float* conv_b = (const float*)d_in[21];
  const float* pw1_w  = (const float*)d_in[22];
  const float* pw1_b  = (const float*)d_in[23];
  const float* dw_w   = (const float*)d_in[24];
  const float* bn_g   = (const float*)d_in[25];
  const float* bn_b   = (const float*)d_in[26];
  const float* bn_m   = (const float*)d_in[27];
  const float* bn_v   = (const float*)d_in[28];
  const float* pw2_w  = (const float*)d_in[29];
  const float* pw2_b  = (const float*)d_in[30];
  const float* ff2_g  = (const float*)d_in[31];
  const float* ff2_b  = (const float*)d_in[32];
  const float* ff2_w1 = (const float*)d_in[33];
  const float* ff2_b1 = (const float*)d_in[34];
  const float* ff2_w2 = (const float*)d_in[35];
  const float* ff2_b2 = (const float*)d_in[36];
  const float* ln_g   = (const float*)d_in[37];
  const float* ln_b   = (const float*)d_in[38];

  float* out  = (float*)d_out;            // [B,S,D] f32
  float* attn = out + ND;                 // [B,H,S,S] f32

  // workspace (f32 units): res ND | ybf ND/2 | big 2ND | psg ND | wts | pebf | ppbf
  float*  res  = (float*)d_ws;
  ushort* ybf  = (ushort*)(res + ND);            // ND ushorts
  float*  big  = (float*)(ybf + ND);             // 2*ND f32
  float*  psgf = big + 2 * ND;                   // ND f32 = 2*ND ushorts
  ushort* wts  = (ushort*)(psgf + ND);           // 6,291,456 ushorts
  ushort* pebf = wts + 6291456;                  // 262,144
  ushort* ppbf = pebf + 262144;                  // 262,144

  // aliases
  ushort* ffmid = (ushort*)big;                  // [M,2048] bf16 (FF phases)
  ushort* qu    = (ushort*)big;                  // [M,512] bf16 (attn phase)
  ushort* qv    = qu + ND;
  ushort* kbb   = qv + ND;
  ushort* vbb   = kbb + ND;
  ushort* psg   = (ushort*)psgf;                 // [64][512][512] bf16 per group
  ushort* vT    = (ushort*)psgf;                 // [256][64][512] bf16 (after groups)
  ushort* ctxbf = ybf;                           // [M,512] bf16
  ushort* glubf = ybf;
  ushort* dwbf  = (ushort*)psgf;

  ushort* ff1w1t = wts;
  ushort* ff1w2t = wts + 1048576;
  ushort* wqt    = wts + 2097152;
  ushort* wkt    = wts + 2359296;
  ushort* wvt    = wts + 2621440;
  ushort* wot    = wts + 2883584;
  ushort* pw1t   = wts + 3145728;
  ushort* pw2t   = wts + 3670016;
  ushort* ff2w1t = wts + 3932160;
  ushort* ff2w2t = wts + 4980736;
  ushort* wpost  = wts + 6029312;

  const dim3 blk(256);

  // ---- weight prep ----
  transpose_bf16<<<dim3(64, 16), blk, 0, stream>>>(ff1_w1, ff1w1t, 512, 2048);
  transpose_bf16<<<dim3(16, 64), blk, 0, stream>>>(ff1_w2, ff1w2t, 2048, 512);
  transpose_bf16<<<dim3(16, 16), blk, 0, stream>>>(wq, wqt, 512, 512);
  transpose_bf16<<<dim3(16, 16), blk, 0, stream>>>(wk, wkt, 512, 512);
  transpose_bf16<<<dim3(16, 16), blk, 0, stream>>>(wv, wvt, 512, 512);
  transpose_bf16<<<dim3(16, 16), blk, 0, stream>>>(wo, wot, 512, 512);
  transpose_bf16<<<dim3(16, 16), blk, 0, stream>>>(wpos, wpost, 512, 512);
  transpose_bf16<<<dim3(32, 16), blk, 0, stream>>>(pw1_w, pw1t, 512, 1024);
  transpose_bf16<<<dim3(16, 16), blk, 0, stream>>>(pw2_w, pw2t, 512, 512);
  transpose_bf16<<<dim3(64, 16), blk, 0, stream>>>(ff2_w1, ff2w1t, 512, 2048);
  transpose_bf16<<<dim3(16, 64), blk, 0, stream>>>(ff2_w2, ff2w2t, 2048, 512);
  pe_kernel_bf16<<<512, blk, 0, stream>>>(pebf);
  gemm_bf16<0, 0, 0, 1><<<dim3(4, 4), blk, 0, stream>>>(pebf, wpost, nullptr, nullptr, ppbf,
                                                        512, 512, 512);

  // ---- Macaron FF1: res = x + 0.5*FF(LN(x)) ----
  ln_bf16<<<NTOK / 4, blk, 0, stream>>>(x, ff1_g, ff1_b, ybf);
  gemm_bf16<1, 0, 1, 1><<<dim3(16, 128), blk, 0, stream>>>(ybf, ff1w1t, ff1_b1, nullptr, ffmid,
                                                           NTOK, 512, 2048);
  gemm_bf16<0, 2, 1, 0><<<dim3(4, 128), blk, 0, stream>>>(ffmid, ff1w2t, ff1_b2, x, res,
                                                          NTOK, 2048, 512);

  // ---- Attention ----
  ln_bf16<<<NTOK / 4, blk, 0, stream>>>(res, attn_g, attn_b, ybf);
  gemm_dual<<<dim3(4, 128), blk, 0, stream>>>(ybf, wqt, bq, u_bias, v_bias, qu, qv,
                                              NTOK, 512, 512);
  gemm_bf16<0, 0, 1, 1><<<dim3(4, 128), blk, 0, stream>>>(ybf, wkt, bk, nullptr, kbb,
                                                          NTOK, 512, 512);
  gemm_bf16<0, 0, 1, 1><<<dim3(4, 128), blk, 0, stream>>>(ybf, wvt, bv, nullptr, vbb,
                                                          NTOK, 512, 512);
  for (int g = 0; g < 4; ++g) {
    ps_gemm<<<dim3(8, 64), blk, 0, stream>>>(qv, ppbf, psg, g * 8);
    attn_fused<<<dim3(8, 64), blk, 0, stream>>>(qu, kbb, psg, attn, g * 8);
  }
  transpose_v<<<dim3(8, 256), blk, 0, stream>>>(vbb, vT);
  attn_ctx_mfma<<<dim3(8, 256), blk, 0, stream>>>(attn, vT, ctxbf);
  gemm_bf16<0, 1, 1, 0><<<dim3(4, 128), blk, 0, stream>>>(ctxbf, wot, bo, res, res,
                                                          NTOK, 512, 512);

  // ---- Conv module ----
  ln_bf16<<<NTOK / 4, blk, 0, stream>>>(res, conv_g, conv_b, ybf);
  gemm_bf16<0, 0, 1, 0><<<dim3(8, 128), blk, 0, stream>>>(ybf, pw1t, pw1_b, nullptr, big,
                                                          NTOK, 512, 1024);
  glu8<<<(int)(ND / 8 / 256), blk, 0, stream>>>(big, glubf);
  dwconv2<<<dim3(4, 8, 32), blk, 0, stream>>>(glubf, dw_w, bn_g, bn_b, bn_m, bn_v, dwbf);
  gemm_bf16<0, 1, 1, 0><<<dim3(4, 128), blk, 0, stream>>>(dwbf, pw2t, pw2_b, res, res,
                                                          NTOK, 512, 512);

  // ---- Macaron FF2 + final LN ----
  ln_bf16<<<NTOK / 4, blk, 0, stream>>>(res, ff2_g, ff2_b, ybf);
  gemm_bf16<1, 0, 1, 1><<<dim3(16, 128), blk, 0, stream>>>(ybf, ff2w1t, ff2_b1, nullptr, ffmid,
                                                           NTOK, 512, 2048);
  gemm_bf16<0, 2, 1, 0><<<dim3(4, 128), blk, 0, stream>>>(ffmid, ff2w2t, ff2_b2, res, res,
                                                          NTOK, 2048, 512);
  ln_f32<<<NTOK / 4, blk, 0, stream>>>(res, ln_g, ln_b, out);
}

// Round 4
// 1005.377 us; speedup vs baseline: 3.7302x; 1.0023x over previous
//
#include <hip/hip_runtime.h>
#include <cstddef>
#include <cstdint>

#define EPSF 1e-5f

constexpr int BB = 32, SS = 512, DD = 512, HH = 8, DH = 64;
constexpr int NTOK = BB * SS;              // 16384 rows
constexpr size_t ND = (size_t)NTOK * DD;   // 8,388,608

typedef __attribute__((ext_vector_type(8))) short bf16x8;
typedef __attribute__((ext_vector_type(4))) float f32x4;

__device__ __forceinline__ float sigmf(float v) { return 1.f / (1.f + __expf(-v)); }

__device__ __forceinline__ ushort f2bf(float f) {
  union { float f; uint32_t u; } x{f};
  uint32_t r = x.u + 0x7FFF + ((x.u >> 16) & 1);
  return (ushort)(r >> 16);
}
__device__ __forceinline__ float bf2f(ushort u) {
  union { uint32_t u; float f; } x{(uint32_t)u << 16};
  return x.f;
}

// async global->LDS, 16B per lane, wave-uniform LDS base + lane*16
__device__ __forceinline__ void gload16(const ushort* g, ushort* ldsbase) {
#if defined(__has_builtin) && __has_builtin(__builtin_amdgcn_global_load_lds)
  __builtin_amdgcn_global_load_lds((const __attribute__((address_space(1))) void*)g,
                                   (__attribute__((address_space(3))) void*)ldsbase, 16, 0, 0);
#else
  const int lane = threadIdx.x & 63;
  *(bf16x8*)(ldsbase + lane * 8) = *(const bf16x8*)g;
#endif
}

// ---------------- LayerNorm: one wave per row, f32 out --------------------------
__global__ __launch_bounds__(256) void ln_f32(const float* __restrict__ x,
                                              const float* __restrict__ g,
                                              const float* __restrict__ b,
                                              float* __restrict__ y) {
  const int lane = threadIdx.x & 63;
  const int row = blockIdx.x * 4 + (threadIdx.x >> 6);
  const float* xr = x + (size_t)row * 512;
  const float4 v0 = *(const float4*)&xr[lane << 2];
  const float4 v1 = *(const float4*)&xr[256 + (lane << 2)];
  float s = v0.x + v0.y + v0.z + v0.w + v1.x + v1.y + v1.z + v1.w;
#pragma unroll
  for (int o = 32; o > 0; o >>= 1) s += __shfl_xor(s, o);
  const float mean = s * (1.f / 512.f);
  float q = 0.f;
  q += (v0.x - mean) * (v0.x - mean); q += (v0.y - mean) * (v0.y - mean);
  q += (v0.z - mean) * (v0.z - mean); q += (v0.w - mean) * (v0.w - mean);
  q += (v1.x - mean) * (v1.x - mean); q += (v1.y - mean) * (v1.y - mean);
  q += (v1.z - mean) * (v1.z - mean); q += (v1.w - mean) * (v1.w - mean);
#pragma unroll
  for (int o = 32; o > 0; o >>= 1) q += __shfl_xor(q, o);
  const float rs = rsqrtf(q * (1.f / 512.f) + EPSF);
  const float4 g0 = *(const float4*)&g[lane << 2];
  const float4 g1 = *(const float4*)&g[256 + (lane << 2)];
  const float4 b0 = *(const float4*)&b[lane << 2];
  const float4 b1 = *(const float4*)&b[256 + (lane << 2)];
  float* yr = y + (size_t)row * 512;
  float4 o0, o1;
  o0.x = (v0.x - mean) * rs * g0.x + b0.x; o0.y = (v0.y - mean) * rs * g0.y + b0.y;
  o0.z = (v0.z - mean) * rs * g0.z + b0.z; o0.w = (v0.w - mean) * rs * g0.w + b0.w;
  o1.x = (v1.x - mean) * rs * g1.x + b1.x; o1.y = (v1.y - mean) * rs * g1.y + b1.y;
  o1.z = (v1.z - mean) * rs * g1.z + b1.z; o1.w = (v1.w - mean) * rs * g1.w + b1.w;
  *(float4*)&yr[lane << 2] = o0;
  *(float4*)&yr[256 + (lane << 2)] = o1;
}

// ---------------- LayerNorm writing bf16 ----------------------------------------
__global__ __launch_bounds__(256) void ln_bf16(const float* __restrict__ x,
                                               const float* __restrict__ g,
                                               const float* __restrict__ b,
                                               ushort* __restrict__ y) {
  const int lane = threadIdx.x & 63;
  const int row = blockIdx.x * 4 + (threadIdx.x >> 6);
  const float* xr = x + (size_t)row * 512;
  const float4 v0 = *(const float4*)&xr[lane << 2];
  const float4 v1 = *(const float4*)&xr[256 + (lane << 2)];
  float s = v0.x + v0.y + v0.z + v0.w + v1.x + v1.y + v1.z + v1.w;
#pragma unroll
  for (int o = 32; o > 0; o >>= 1) s += __shfl_xor(s, o);
  const float mean = s * (1.f / 512.f);
  float q = 0.f;
  q += (v0.x - mean) * (v0.x - mean); q += (v0.y - mean) * (v0.y - mean);
  q += (v0.z - mean) * (v0.z - mean); q += (v0.w - mean) * (v0.w - mean);
  q += (v1.x - mean) * (v1.x - mean); q += (v1.y - mean) * (v1.y - mean);
  q += (v1.z - mean) * (v1.z - mean); q += (v1.w - mean) * (v1.w - mean);
#pragma unroll
  for (int o = 32; o > 0; o >>= 1) q += __shfl_xor(q, o);
  const float rs = rsqrtf(q * (1.f / 512.f) + EPSF);
  const float4 g0 = *(const float4*)&g[lane << 2];
  const float4 g1 = *(const float4*)&g[256 + (lane << 2)];
  const float4 b0 = *(const float4*)&b[lane << 2];
  const float4 b1 = *(const float4*)&b[256 + (lane << 2)];
  ushort* yr = y + (size_t)row * 512;
  ushort4 o0, o1;
  o0.x = f2bf((v0.x - mean) * rs * g0.x + b0.x); o0.y = f2bf((v0.y - mean) * rs * g0.y + b0.y);
  o0.z = f2bf((v0.z - mean) * rs * g0.z + b0.z); o0.w = f2bf((v0.w - mean) * rs * g0.w + b0.w);
  o1.x = f2bf((v1.x - mean) * rs * g1.x + b1.x); o1.y = f2bf((v1.y - mean) * rs * g1.y + b1.y);
  o1.z = f2bf((v1.z - mean) * rs * g1.z + b1.z); o1.w = f2bf((v1.w - mean) * rs * g1.w + b1.w);
  *(ushort4*)&yr[lane << 2] = o0;
  *(ushort4*)&yr[256 + (lane << 2)] = o1;
}

// ---------------- Weight transpose + bf16 convert: [K,N] f32 -> [N,K] bf16 ------
__global__ __launch_bounds__(256) void transpose_bf16(const float* __restrict__ in,
                                                      ushort* __restrict__ out,
                                                      int K, int N) {
  __shared__ float tile[32][33];
  const int tx = threadIdx.x & 31, ty = threadIdx.x >> 5;
  const int n0 = blockIdx.x << 5, k0 = blockIdx.y << 5;
#pragma unroll
  for (int i = 0; i < 32; i += 8)
    tile[ty + i][tx] = in[(size_t)(k0 + ty + i) * N + n0 + tx];
  __syncthreads();
#pragma unroll
  for (int i = 0; i < 32; i += 8)
    out[(size_t)(n0 + ty + i) * K + k0 + tx] = f2bf(tile[tx][ty + i]);
}

// ---------------- bf16 MFMA GEMM (m97 structure): C = epi(A * Wt^T + bias) ------
// 128x128 tile, BK=64, linear LDS, global_load_lds(16B) staging, 2 barriers/K-step
template <int ACT, int RES, int HB, int OBF>
__global__ __launch_bounds__(256) void gemm_bf16(const ushort* __restrict__ A,
                                                 const ushort* __restrict__ Wt,
                                                 const float* __restrict__ bias,
                                                 const float* __restrict__ res,
                                                 void* __restrict__ Cv,
                                                 int M, int K, int N) {
  __shared__ ushort Al[128 * 64];
  __shared__ ushort Bl[128 * 64];
  const int t = threadIdx.x;
  const int lane = t & 63;
  const int w = t >> 6;
  const int wr = (w >> 1) << 6, wc = (w & 1) << 6;
  const int m0 = blockIdx.y << 7, n0 = blockIdx.x << 7;
  const int lm = lane & 15;
  const int grow = lane >> 3;          // 0..7
  const int gcol = (lane & 7) << 3;    // ushort offset 0..56

  f32x4 acc[4][4];
#pragma unroll
  for (int i = 0; i < 4; ++i)
#pragma unroll
    for (int j = 0; j < 4; ++j) acc[i][j] = (f32x4)(0.f);

  const int NT = K >> 6;
  for (int tt = 0; tt < NT; ++tt) {
    const int k0 = tt << 6;
    if (tt) __syncthreads();
#pragma unroll
    for (int i = 0; i < 4; ++i) {
      const int s = (w << 2) + i;                 // 16 call slots, 8 rows each
      gload16(A + (size_t)(m0 + (s << 3) + grow) * K + k0 + gcol, &Al[s << 9]);
      gload16(Wt + (size_t)(n0 + (s << 3) + grow) * K + k0 + gcol, &Bl[s << 9]);
    }
    __syncthreads();
#pragma unroll
    for (int ks = 0; ks < 2; ++ks) {
      const int kof = (ks << 5) + ((lane >> 4) << 3);
      bf16x8 af[4], bfr[4];
#pragma unroll
      for (int i = 0; i < 4; ++i) af[i] = *(const bf16x8*)&Al[(wr + (i << 4) + lm) * 64 + kof];
#pragma unroll
      for (int j = 0; j < 4; ++j) bfr[j] = *(const bf16x8*)&Bl[(wc + (j << 4) + lm) * 64 + kof];
#pragma unroll
      for (int i = 0; i < 4; ++i)
#pragma unroll
        for (int j = 0; j < 4; ++j)
          acc[i][j] = __builtin_amdgcn_mfma_f32_16x16x32_bf16(af[i], bfr[j], acc[i][j], 0, 0, 0);
    }
  }

  float bb[4] = {0.f, 0.f, 0.f, 0.f};
  if (HB) {
#pragma unroll
    for (int j = 0; j < 4; ++j) bb[j] = bias[n0 + wc + j * 16 + lm];
  }
  const int rbase = m0 + wr + ((lane >> 4) << 2);
#pragma unroll
  for (int i = 0; i < 4; ++i) {
#pragma unroll
    for (int r = 0; r < 4; ++r) {
      const size_t row = (size_t)(rbase + i * 16 + r);
#pragma unroll
      for (int j = 0; j < 4; ++j) {
        const int col = n0 + wc + j * 16 + lm;
        float v = acc[i][j][r] + bb[j];
        if (ACT == 1) v = v * sigmf(v);
        if (RES == 1) v += res[row * N + col];
        else if (RES == 2) v = res[row * N + col] + 0.5f * v;
        if (OBF) ((ushort*)Cv)[row * N + col] = f2bf(v);
        else ((float*)Cv)[row * N + col] = v;
      }
    }
  }
}

// ---------------- dual-output Q projection: qu = q+bq+u, qv = q+bq+v ------------
__global__ __launch_bounds__(256) void gemm_dual(const ushort* __restrict__ A,
                                                 const ushort* __restrict__ Wt,
                                                 const float* __restrict__ bias,
                                                 const float* __restrict__ ub,
                                                 const float* __restrict__ vb,
                                                 ushort* __restrict__ qu,
                                                 ushort* __restrict__ qv,
                                                 int M, int K, int N) {
  __shared__ ushort Al[128 * 64];
  __shared__ ushort Bl[128 * 64];
  const int t = threadIdx.x;
  const int lane = t & 63;
  const int w = t >> 6;
  const int wr = (w >> 1) << 6, wc = (w & 1) << 6;
  const int m0 = blockIdx.y << 7, n0 = blockIdx.x << 7;
  const int lm = lane & 15;
  const int grow = lane >> 3;
  const int gcol = (lane & 7) << 3;
  f32x4 acc[4][4];
#pragma unroll
  for (int i = 0; i < 4; ++i)
#pragma unroll
    for (int j = 0; j < 4; ++j) acc[i][j] = (f32x4)(0.f);
  const int NT = K >> 6;
  for (int tt = 0; tt < NT; ++tt) {
    const int k0 = tt << 6;
    if (tt) __syncthreads();
#pragma unroll
    for (int i = 0; i < 4; ++i) {
      const int s = (w << 2) + i;
      gload16(A + (size_t)(m0 + (s << 3) + grow) * K + k0 + gcol, &Al[s << 9]);
      gload16(Wt + (size_t)(n0 + (s << 3) + grow) * K + k0 + gcol, &Bl[s << 9]);
    }
    __syncthreads();
#pragma unroll
    for (int ks = 0; ks < 2; ++ks) {
      const int kof = (ks << 5) + ((lane >> 4) << 3);
      bf16x8 af[4], bfr[4];
#pragma unroll
      for (int i = 0; i < 4; ++i) af[i] = *(const bf16x8*)&Al[(wr + (i << 4) + lm) * 64 + kof];
#pragma unroll
      for (int j = 0; j < 4; ++j) bfr[j] = *(const bf16x8*)&Bl[(wc + (j << 4) + lm) * 64 + kof];
#pragma unroll
      for (int i = 0; i < 4; ++i)
#pragma unroll
        for (int j = 0; j < 4; ++j)
          acc[i][j] = __builtin_amdgcn_mfma_f32_16x16x32_bf16(af[i], bfr[j], acc[i][j], 0, 0, 0);
    }
  }
  const int rbase = m0 + wr + ((lane >> 4) << 2);
#pragma unroll
  for (int i = 0; i < 4; ++i) {
#pragma unroll
    for (int r = 0; r < 4; ++r) {
      const size_t row = (size_t)(rbase + i * 16 + r);
#pragma unroll
      for (int j = 0; j < 4; ++j) {
        const int col = n0 + wc + j * 16 + lm;
        const float v = acc[i][j][r] + bias[col];
        qu[row * N + col] = f2bf(v + ub[col]);
        qv[row * N + col] = f2bf(v + vb[col]);
      }
    }
  }
}

// ------------- Sinusoidal PE (bf16) ---------------------------------------------
__global__ void pe_kernel_bf16(ushort* __restrict__ pe) {
  const int pos = blockIdx.x, ii = threadIdx.x;
  const float ang = (float)pos * powf(10000.f, -(float)(2 * ii) / 512.f);
  pe[((size_t)pos << 9) + 2 * ii] = f2bf(sinf(ang));
  pe[((size_t)pos << 9) + 2 * ii + 1] = f2bf(cosf(ang));
}

// ------------- PS = (q+v) . pp^T per (b,h): psg[z][q][j] bf16 -------------------
__global__ __launch_bounds__(256) void ps_gemm(const ushort* __restrict__ qv,
                                               const ushort* __restrict__ ppb,
                                               ushort* __restrict__ psg,
                                               const int b0) {
  __shared__ ushort Plds[2][128][72];
  const int t = threadIdx.x, lane = t & 63, w = t >> 6;
  const int z = blockIdx.y;
  const int b = b0 + (z >> 3), h = z & 7;
  const int q0 = blockIdx.x << 6;
  const int lm = lane & 15, lk = (lane >> 4) << 3;
  const size_t abase = ((size_t)((b << 9) + q0 + (w << 4) + lm)) * 512 + (h << 6) + lk;
  const bf16x8 af0 = *(const bf16x8*)&qv[abase];
  const bf16x8 af1 = *(const bf16x8*)&qv[abase + 32];
  const int srow = t >> 3, scol = (t & 7) << 3;
  const ushort* pbase = ppb + (h << 6);
  f32x4 acc[32];
#pragma unroll
  for (int i = 0; i < 32; ++i) acc[i] = (f32x4)(0.f);
  bf16x8 kreg[4];
#pragma unroll
  for (int it = 0; it < 4; ++it)
    kreg[it] = *(const bf16x8*)&pbase[(size_t)((it << 5) + srow) * 512 + scol];
#pragma unroll
  for (int it = 0; it < 4; ++it) *(bf16x8*)&Plds[0][(it << 5) + srow][scol] = kreg[it];
  int cur = 0;
#pragma unroll
  for (int tile = 0; tile < 4; ++tile) {
    if (tile < 3) {
#pragma unroll
      for (int it = 0; it < 4; ++it)
        kreg[it] = *(const bf16x8*)&pbase[(size_t)((tile + 1) * 128 + (it << 5) + srow) * 512 + scol];
    }
    __syncthreads();
    if (tile < 3) {
#pragma unroll
      for (int it = 0; it < 4; ++it) *(bf16x8*)&Plds[cur ^ 1][(it << 5) + srow][scol] = kreg[it];
    }
#pragma unroll
    for (int sct = 0; sct < 8; ++sct) {
      const int ct = (tile << 3) + sct;
      const bf16x8 bf0 = *(const bf16x8*)&Plds[cur][(sct << 4) + lm][lk];
      const bf16x8 bf1 = *(const bf16x8*)&Plds[cur][(sct << 4) + lm][lk + 32];
      acc[ct] = __builtin_amdgcn_mfma_f32_16x16x32_bf16(af0, bf0, acc[ct], 0, 0, 0);
      acc[ct] = __builtin_amdgcn_mfma_f32_16x16x32_bf16(af1, bf1, acc[ct], 0, 0, 0);
    }
    cur ^= 1;
  }
  ushort* prow = psg + ((size_t)z << 18);
  const int qb_ = q0 + (w << 4) + ((lane >> 4) << 2);
#pragma unroll
  for (int ct = 0; ct < 32; ++ct)
#pragma unroll
    for (int r = 0; r < 4; ++r)
      prow[(size_t)(qb_ + r) * 512 + (ct << 4) + lm] = f2bf(acc[ct][r]);
}

// ------------- fused: content-MFMA + rel-shift + softmax + attn-write + PV ------
__global__ __launch_bounds__(256) void attn_fused2(const ushort* __restrict__ qu,
                                                   const ushort* __restrict__ kbb,
                                                   const ushort* __restrict__ psg,
                                                   const ushort* __restrict__ vT,
                                                   float* __restrict__ attn,
                                                   ushort* __restrict__ ctx,
                                                   const int b0) {
  __shared__ union SMem {
    ushort k[2][128][72];
    ushort pv[2][64][136];  // [0]=P chunk [64q][128c], [1]=V^T chunk [64d][128c]
  } sm;
  const int t = threadIdx.x, lane = t & 63, w = t >> 6;
  const int z = blockIdx.y;
  const int b = b0 + (z >> 3), h = z & 7;
  const int q0 = blockIdx.x << 6;
  const int lm = lane & 15, lk = (lane >> 4) << 3;
  const size_t abase = ((size_t)((b << 9) + q0 + (w << 4) + lm)) * 512 + (h << 6) + lk;
  const bf16x8 af0 = *(const bf16x8*)&qu[abase];
  const bf16x8 af1 = *(const bf16x8*)&qu[abase + 32];
  const int srow = t >> 3, scol = (t & 7) << 3;
  const ushort* kbase = kbb + ((size_t)(b << 9)) * 512 + (h << 6);
  f32x4 acc[32];
#pragma unroll
  for (int i = 0; i < 32; ++i) acc[i] = (f32x4)(0.f);
  bf16x8 kreg[4];
#pragma unroll
  for (int it = 0; it < 4; ++it)
    kreg[it] = *(const bf16x8*)&kbase[(size_t)((it << 5) + srow) * 512 + scol];
#pragma unroll
  for (int it = 0; it < 4; ++it) *(bf16x8*)&sm.k[0][(it << 5) + srow][scol] = kreg[it];
  int cur = 0;
#pragma unroll
  for (int tile = 0; tile < 4; ++tile) {
    if (tile < 3) {
#pragma unroll
      for (int it = 0; it < 4; ++it)
        kreg[it] = *(const bf16x8*)&kbase[(size_t)((tile + 1) * 128 + (it << 5) + srow) * 512 + scol];
    }
    __syncthreads();
    if (tile < 3) {
#pragma unroll
      for (int it = 0; it < 4; ++it) *(bf16x8*)&sm.k[cur ^ 1][(it << 5) + srow][scol] = kreg[it];
    }
#pragma unroll
    for (int sct = 0; sct < 8; ++sct) {
      const int ct = (tile << 3) + sct;
      const bf16x8 bf0 = *(const bf16x8*)&sm.k[cur][(sct << 4) + lm][lk];
      const bf16x8 bf1 = *(const bf16x8*)&sm.k[cur][(sct << 4) + lm][lk + 32];
      acc[ct] = __builtin_amdgcn_mfma_f32_16x16x32_bf16(af0, bf0, acc[ct], 0, 0, 0);
      acc[ct] = __builtin_amdgcn_mfma_f32_16x16x32_bf16(af1, bf1, acc[ct], 0, 0, 0);
    }
    cur ^= 1;
  }
  // rel-shift gather from psg + scale
  const float scale = 0.044194173824159216f;  // 1/sqrt(512)
  const ushort* prow = psg + ((size_t)z << 18);
  const int qb_ = q0 + (w << 4) + ((lane >> 4) << 2);
#pragma unroll
  for (int ct = 0; ct < 32; ++ct) {
#pragma unroll
    for (int r = 0; r < 4; ++r) {
      const int q = qb_ + r;
      const int c = (ct << 4) + lm;
      float f;
      if (c <= q)          f = bf2f(prow[(size_t)q * 512 + c - q + 511]);
      else if (c == q + 1) f = 0.f;
      else                 f = bf2f(prow[(size_t)(q + 1) * 512 + c - q - 2]);
      acc[ct][r] = (acc[ct][r] + f) * scale;
    }
  }
  // softmax over c (512) per row
  float mx[4] = {-3.0e38f, -3.0e38f, -3.0e38f, -3.0e38f};
#pragma unroll
  for (int ct = 0; ct < 32; ++ct)
#pragma unroll
    for (int r = 0; r < 4; ++r) mx[r] = fmaxf(mx[r], acc[ct][r]);
#pragma unroll
  for (int o = 1; o < 16; o <<= 1)
#pragma unroll
    for (int r = 0; r < 4; ++r) mx[r] = fmaxf(mx[r], __shfl_xor(mx[r], o));
  float sme[4] = {0.f, 0.f, 0.f, 0.f};
#pragma unroll
  for (int ct = 0; ct < 32; ++ct)
#pragma unroll
    for (int r = 0; r < 4; ++r) {
      acc[ct][r] = __expf(acc[ct][r] - mx[r]);
      sme[r] += acc[ct][r];
    }
#pragma unroll
  for (int o = 1; o < 16; o <<= 1)
#pragma unroll
    for (int r = 0; r < 4; ++r) sme[r] += __shfl_xor(sme[r], o);
#pragma unroll
  for (int r = 0; r < 4; ++r) {
    const float inv = 1.f / sme[r];
#pragma unroll
    for (int ct = 0; ct < 32; ++ct) acc[ct][r] *= inv;
  }
  // write attn f32 (required output)
  float* arow = attn + ((size_t)((b << 3) + h) << 18);
#pragma unroll
  for (int ct = 0; ct < 32; ++ct)
#pragma unroll
    for (int r = 0; r < 4; ++r)
      arow[(size_t)(qb_ + r) * 512 + (ct << 4) + lm] = acc[ct][r];
  // ---- PV: ctx[q][d] = sum_c P[q][c] V[c][d], via ctx^T = V^T . P^T -------------
  f32x4 acc2[4];
#pragma unroll
  for (int i = 0; i < 4; ++i) acc2[i] = (f32x4)(0.f);
  const ushort* vtb = vT + (((size_t)z) << 6) * 512;   // vT[(z*64+d)*512 + s]
  const int qloc = (w << 4) + ((lane >> 4) << 2);
  for (int ck = 0; ck < 4; ++ck) {
    __syncthreads();
    // P chunk -> LDS (bf16)
#pragma unroll
    for (int sct = 0; sct < 8; ++sct) {
      const int ct = (ck << 3) + sct;
#pragma unroll
      for (int r = 0; r < 4; ++r)
        sm.pv[0][qloc + r][(sct << 4) + lm] = f2bf(acc[ct][r]);
    }
    // V^T chunk -> LDS
    {
      const int d = t >> 2;
      const int c8 = (t & 3) << 5;
      const ushort* src = vtb + (size_t)d * 512 + (ck << 7) + c8;
#pragma unroll
      for (int u = 0; u < 4; ++u)
        *(bf16x8*)&sm.pv[1][d][c8 + (u << 3)] = *(const bf16x8*)(src + (u << 3));
    }
    __syncthreads();
#pragma unroll
    for (int ks = 0; ks < 4; ++ks) {
      const int kof = (ks << 5) + lk;
      const bf16x8 pb = *(const bf16x8*)&sm.pv[0][(w << 4) + lm][kof];
#pragma unroll
      for (int dt = 0; dt < 4; ++dt) {
        const bf16x8 va = *(const bf16x8*)&sm.pv[1][(dt << 4) + lm][kof];
        acc2[dt] = __builtin_amdgcn_mfma_f32_16x16x32_bf16(va, pb, acc2[dt], 0, 0, 0);
      }
    }
  }
  // D layout: col(lane&15)=q-offset, row((lane>>4)*4+r)=d-offset -> 4 consecutive d
  const int qq = q0 + (w << 4) + lm;
  const int dbase = (lane >> 4) << 2;
#pragma unroll
  for (int dt = 0; dt < 4; ++dt) {
    ushort4 o;
    o.x = f2bf(acc2[dt][0]); o.y = f2bf(acc2[dt][1]);
    o.z = f2bf(acc2[dt][2]); o.w = f2bf(acc2[dt][3]);
    *(ushort4*)&ctx[((size_t)((b << 9) + qq)) * 512 + (h << 6) + (dt << 4) + dbase] = o;
  }
}

// ------------- V transpose: vbb [b,s,h*64+dh] -> vT [bh][dh][s] -----------------
__global__ __launch_bounds__(256) void transpose_v(const ushort* __restrict__ vbb,
                                                   ushort* __restrict__ vT) {
  __shared__ ushort tl[64][72];
  const int t = threadIdx.x;
  const int s0 = blockIdx.x << 6;
  const int z = blockIdx.y;
  const int b = z >> 3, h = z & 7;
  const int srow = t >> 3, scol = (t & 7) << 3;
#pragma unroll
  for (int it = 0; it < 2; ++it) {
    const int r = (it << 5) + srow;
    *(bf16x8*)&tl[r][scol] =
        *(const bf16x8*)&vbb[((size_t)((b << 9) + s0 + r)) * 512 + (h << 6) + scol];
  }
  __syncthreads();
#pragma unroll
  for (int it = 0; it < 2; ++it) {
    const int dh = (it << 5) + srow;
    ushort tmp[8];
#pragma unroll
    for (int k = 0; k < 8; ++k) tmp[k] = tl[scol + k][dh];
    *(bf16x8*)&vT[((size_t)((z << 6) + dh)) * 512 + s0 + scol] = *(bf16x8*)tmp;
  }
}

// ------------- GLU vectorized: f32 [M,1024] -> bf16 [M,512] ---------------------
__global__ __launch_bounds__(256) void glu8(const float* __restrict__ mid,
                                            ushort* __restrict__ out) {
  const int tid = blockIdx.x * 256 + threadIdx.x;
  const int r = tid >> 6;
  const int c = (tid & 63) << 3;
  const float* mrow = mid + ((size_t)r << 10);
  const float4 a0 = *(const float4*)&mrow[c];
  const float4 a1 = *(const float4*)&mrow[c + 4];
  const float4 g0 = *(const float4*)&mrow[512 + c];
  const float4 g1 = *(const float4*)&mrow[512 + c + 4];
  ushort tmp[8];
  tmp[0] = f2bf(a0.x * sigmf(g0.x)); tmp[1] = f2bf(a0.y * sigmf(g0.y));
  tmp[2] = f2bf(a0.z * sigmf(g0.z)); tmp[3] = f2bf(a0.w * sigmf(g0.w));
  tmp[4] = f2bf(a1.x * sigmf(g1.x)); tmp[5] = f2bf(a1.y * sigmf(g1.y));
  tmp[6] = f2bf(a1.z * sigmf(g1.z)); tmp[7] = f2bf(a1.w * sigmf(g1.w));
  *(bf16x8*)&out[((size_t)r << 9) + c] = *(bf16x8*)tmp;
}

// ------------- depthwise conv (K=31) + BN + swish, register sliding window ------
__global__ __launch_bounds__(256) void dwconv2(const ushort* __restrict__ in,
                                               const float* __restrict__ w,
                                               const float* __restrict__ bng,
                                               const float* __restrict__ bnb,
                                               const float* __restrict__ bnm,
                                               const float* __restrict__ bnv,
                                               ushort* __restrict__ out) {
  __shared__ float wl[31][128];
  const int t = threadIdx.x;
  const int dbase = blockIdx.x << 7;
  const int b = blockIdx.z;
  const int sb = (blockIdx.y << 6) + ((t >> 6) << 4);
  if (t < 128) {
    const float* ws = &w[(dbase + t) * 31];
#pragma unroll
    for (int k = 0; k < 31; ++k) wl[k][t] = ws[k];
  }
  __syncthreads();
  const int dl = (t & 63) << 1;
  const int d = dbase + dl;
  const size_t base = (((size_t)b) << 18) + d;
  float2 win[46];
#pragma unroll
  for (int i = 0; i < 46; ++i) {
    const int s = sb - 15 + i;
    if (s >= 0 && s < 512) {
      const ushort2 u = *(const ushort2*)&in[base + ((size_t)s << 9)];
      win[i].x = bf2f(u.x); win[i].y = bf2f(u.y);
    } else {
      win[i].x = 0.f; win[i].y = 0.f;
    }
  }
  float2 acc[16];
#pragma unroll
  for (int p = 0; p < 16; ++p) { acc[p].x = 0.f; acc[p].y = 0.f; }
#pragma unroll
  for (int k = 0; k < 31; ++k) {
    const float2 w2 = *(const float2*)&wl[k][dl];
#pragma unroll
    for (int p = 0; p < 16; ++p) {
      acc[p].x = fmaf(win[p + k].x, w2.x, acc[p].x);
      acc[p].y = fmaf(win[p + k].y, w2.y, acc[p].y);
    }
  }
  const float g0 = bng[d] * rsqrtf(bnv[d] + EPSF);
  const float g1 = bng[d + 1] * rsqrtf(bnv[d + 1] + EPSF);
  const float m0 = bnm[d], m1 = bnm[d + 1];
  const float bb0 = bnb[d], bb1 = bnb[d + 1];
#pragma unroll
  for (int p = 0; p < 16; ++p) {
    float v0 = (acc[p].x - m0) * g0 + bb0;
    float v1 = (acc[p].y - m1) * g1 + bb1;
    v0 = v0 * sigmf(v0);
    v1 = v1 * sigmf(v1);
    ushort2 o;
    o.x = f2bf(v0); o.y = f2bf(v1);
    *(ushort2*)&out[base + ((size_t)(sb + p) << 9)] = o;
  }
}

extern "C" void kernel_launch(void* const* d_in, const int* in_sizes, int n_in,
                              void* d_out, int out_size, void* d_ws, size_t ws_size,
                              hipStream_t stream) {
  const float* x      = (const float*)d_in[0];
  const float* ff1_g  = (const float*)d_in[1];
  const float* ff1_b  = (const float*)d_in[2];
  const float* ff1_w1 = (const float*)d_in[3];
  const float* ff1_b1 = (const float*)d_in[4];
  const float* ff1_w2 = (const float*)d_in[5];
  const float* ff1_b2 = (const float*)d_in[6];
  const float* attn_g = (const float*)d_in[7];
  const float* attn_b = (const float*)d_in[8];
  const float* wq     = (const float*)d_in[9];
  const float* bq     = (const float*)d_in[10];
  const float* wk     = (const float*)d_in[11];
  const float* bk     = (const float*)d_in[12];
  const float* wv     = (const float*)d_in[13];
  const float* bv     = (const float*)d_in[14];
  const float* wpos   = (const float*)d_in[15];
  const float* u_bias = (const float*)d_in[16];
  const float* v_bias = (const float*)d_in[17];
  const float* wo     = (const float*)d_in[18];
  const float* bo     = (const float*)d_in[19];
  const float* conv_g = (const float*)d_in[20];
  const float* conv_b = (const float*)d_in[21];
  const float* pw1_w  = (const float*)d_in[22];
  const float* pw1_b  = (const float*)d_in[23];
  const float* dw_w   = (const float*)d_in[24];
  const float* bn_g   = (const float*)d_in[25];
  const float* bn_b   = (const float*)d_in[26];
  const float* bn_m   = (const float*)d_in[27];
  const float* bn_v   = (const float*)d_in[28];
  const float* pw2_w  = (const float*)d_in[29];
  const float* pw2_b  = (const float*)d_in[30];
  const float* ff2_g  = (const float*)d_in[31];
  const float* ff2_b  = (const float*)d_in[32];
  const float* ff2_w1 = (const float*)d_in[33];
  const float* ff2_b1 = (const float*)d_in[34];
  const float* ff2_w2 = (const float*)d_in[35];
  const float* ff2_b2 = (const float*)d_in[36];
  const float* ln_g   = (const float*)d_in[37];
  const float* ln_b   = (const float*)d_in[38];

  float* out  = (float*)d_out;            // [B,S,D] f32
  float* attn = out + ND;                 // [B,H,S,S] f32

  // workspace: res ND | ybf ND/2 | big 2ND | psgf ND | wts | pebf | ppbf | vT
  float*  res  = (float*)d_ws;
  ushort* ybf  = (ushort*)(res + ND);            // ND ushorts
  float*  big  = (float*)(ybf + ND);             // 2*ND f32
  float*  psgf = big + 2 * ND;                   // ND f32 = 2*ND ushorts
  ushort* wts  = (ushort*)(psgf + ND);           // 6,291,456 ushorts
  ushort* pebf = wts + 6291456;                  // 262,144
  ushort* ppbf = pebf + 262144;                  // 262,144
  ushort* vT   = ppbf + 262144;                  // 8,388,608 ushorts [256][64][512]

  // aliases
  ushort* ffmid = (ushort*)big;                  // [M,2048] bf16 (FF phases)
  ushort* qu    = (ushort*)big;                  // [M,512] bf16 (attn phase)
  ushort* qv    = qu + ND;
  ushort* kbb   = qv + ND;
  ushort* vbb   = kbb + ND;
  ushort* psg   = (ushort*)psgf;                 // [64][512][512] bf16 per group
  ushort* ctxbf = ybf;                           // [M,512] bf16
  ushort* glubf = ybf;
  ushort* dwbf  = (ushort*)psgf;

  ushort* ff1w1t = wts;
  ushort* ff1w2t = wts + 1048576;
  ushort* wqt    = wts + 2097152;
  ushort* wkt    = wts + 2359296;
  ushort* wvt    = wts + 2621440;
  ushort* wot    = wts + 2883584;
  ushort* pw1t   = wts + 3145728;
  ushort* pw2t   = wts + 3670016;
  ushort* ff2w1t = wts + 3932160;
  ushort* ff2w2t = wts + 4980736;
  ushort* wpost  = wts + 6029312;

  const dim3 blk(256);

  // ---- weight prep ----
  transpose_bf16<<<dim3(64, 16), blk, 0, stream>>>(ff1_w1, ff1w1t, 512, 2048);
  transpose_bf16<<<dim3(16, 64), blk, 0, stream>>>(ff1_w2, ff1w2t, 2048, 512);
  transpose_bf16<<<dim3(16, 16), blk, 0, stream>>>(wq, wqt, 512, 512);
  transpose_bf16<<<dim3(16, 16), blk, 0, stream>>>(wk, wkt, 512, 512);
  transpose_bf16<<<dim3(16, 16), blk, 0, stream>>>(wv, wvt, 512, 512);
  transpose_bf16<<<dim3(16, 16), blk, 0, stream>>>(wo, wot, 512, 512);
  transpose_bf16<<<dim3(16, 16), blk, 0, stream>>>(wpos, wpost, 512, 512);
  transpose_bf16<<<dim3(32, 16), blk, 0, stream>>>(pw1_w, pw1t, 512, 1024);
  transpose_bf16<<<dim3(16, 16), blk, 0, stream>>>(pw2_w, pw2t, 512, 512);
  transpose_bf16<<<dim3(64, 16), blk, 0, stream>>>(ff2_w1, ff2w1t, 512, 2048);
  transpose_bf16<<<dim3(16, 64), blk, 0, stream>>>(ff2_w2, ff2w2t, 2048, 512);
  pe_kernel_bf16<<<512, blk, 0, stream>>>(pebf);
  gemm_bf16<0, 0, 0, 1><<<dim3(4, 4), blk, 0, stream>>>(pebf, wpost, nullptr, nullptr, ppbf,
                                                        512, 512, 512);

  // ---- Macaron FF1: res = x + 0.5*FF(LN(x)) ----
  ln_bf16<<<NTOK / 4, blk, 0, stream>>>(x, ff1_g, ff1_b, ybf);
  gemm_bf16<1, 0, 1, 1><<<dim3(16, 128), blk, 0, stream>>>(ybf, ff1w1t, ff1_b1, nullptr, ffmid,
                                                           NTOK, 512, 2048);
  gemm_bf16<0, 2, 1, 0><<<dim3(4, 128), blk, 0, stream>>>(ffmid, ff1w2t, ff1_b2, x, res,
                                                          NTOK, 2048, 512);

  // ---- Attention ----
  ln_bf16<<<NTOK / 4, blk, 0, stream>>>(res, attn_g, attn_b, ybf);
  gemm_dual<<<dim3(4, 128), blk, 0, stream>>>(ybf, wqt, bq, u_bias, v_bias, qu, qv,
                                              NTOK, 512, 512);
  gemm_bf16<0, 0, 1, 1><<<dim3(4, 128), blk, 0, stream>>>(ybf, wkt, bk, nullptr, kbb,
                                                          NTOK, 512, 512);
  gemm_bf16<0, 0, 1, 1><<<dim3(4, 128), blk, 0, stream>>>(ybf, wvt, bv, nullptr, vbb,
                                                          NTOK, 512, 512);
  transpose_v<<<dim3(8, 256), blk, 0, stream>>>(vbb, vT);
  for (int g = 0; g < 4; ++g) {
    ps_gemm<<<dim3(8, 64), blk, 0, stream>>>(qv, ppbf, psg, g * 8);
    attn_fused2<<<dim3(8, 64), blk, 0, stream>>>(qu, kbb, psg, vT, attn, ctxbf, g * 8);
  }
  gemm_bf16<0, 1, 1, 0><<<dim3(4, 128), blk, 0, stream>>>(ctxbf, wot, bo, res, res,
                                                          NTOK, 512, 512);

  // ---- Conv module ----
  ln_bf16<<<NTOK / 4, blk, 0, stream>>>(res, conv_g, conv_b, ybf);
  gemm_bf16<0, 0, 1, 0><<<dim3(8, 128), blk, 0, stream>>>(ybf, pw1t, pw1_b, nullptr, big,
                                                          NTOK, 512, 1024);
  glu8<<<(int)(ND / 8 / 256), blk, 0, stream>>>(big, glubf);
  dwconv2<<<dim3(4, 8, 32), blk, 0, stream>>>(glubf, dw_w, bn_g, bn_b, bn_m, bn_v, dwbf);
  gemm_bf16<0, 1, 1, 0><<<dim3(4, 128), blk, 0, stream>>>(dwbf, pw2t, pw2_b, res, res,
                                                          NTOK, 512, 512);

  // ---- Macaron FF2 + final LN ----
  ln_bf16<<<NTOK / 4, blk, 0, stream>>>(res, ff2_g, ff2_b, ybf);
  gemm_bf16<1, 0, 1, 1><<<dim3(16, 128), blk, 0, stream>>>(ybf, ff2w1t, ff2_b1, nullptr, ffmid,
                                                           NTOK, 512, 2048);
  gemm_bf16<0, 2, 1, 0><<<dim3(4, 128), blk, 0, stream>>>(ffmid, ff2w2t, ff2_b2, res, res,
                                                          NTOK, 2048, 512);
  ln_f32<<<NTOK / 4, blk, 0, stream>>>(res, ln_g, ln_b, out);
}